// Round 1
// baseline (1501.076 us; speedup 1.0000x reference)
//
#include <hip/hip_runtime.h>
#include <math.h>

#define BB 8
#define LL 2048
#define DM 256
#define NH 8
#define DH 32
#define DFF 1024
#define SS 40
#define UU 40
#define BL (BB*LL)   // 16384

// ---------------------------------------------------------------------------
// Generic tiled fp32 GEMM: C = A(MxK) @ W(KxN) + bias, optional ReLU,
// optional output re-layout to (B,H,L,DH) for attention tensors.
// Block: 256 threads, 64x64 tile, BK=16, 4x4 micro-tile per thread.
// ---------------------------------------------------------------------------
template<int RELU, int OUT_BHLD>
__global__ __launch_bounds__(256)
void gemm_k(const float* __restrict__ A, const float* __restrict__ W,
            const float* __restrict__ bias, float* __restrict__ C,
            int M, int N, int K)
{
    __shared__ float As[16][68];   // [k][row], padded to break store conflicts
    __shared__ float Ws[16][64];   // [k][col]

    const int t    = threadIdx.x;
    const int row0 = blockIdx.x * 64;
    const int col0 = blockIdx.y * 64;

    const int ar  = t >> 2;          // A-load row 0..63
    const int ak  = (t & 3) << 2;    // A-load k offset 0,4,8,12
    const int wkk = t >> 4;          // W-load k 0..15
    const int wc  = (t & 15) << 2;   // W-load col offset
    const int tr  = t >> 4;          // micro-tile row group 0..15
    const int tc  = t & 15;          // micro-tile col group 0..15

    float acc[4][4] = {{0.f,0.f,0.f,0.f},{0.f,0.f,0.f,0.f},
                       {0.f,0.f,0.f,0.f},{0.f,0.f,0.f,0.f}};

    for (int k0 = 0; k0 < K; k0 += 16) {
        float4 a = *(const float4*)(A + (size_t)(row0 + ar) * K + k0 + ak);
        float4 w = *(const float4*)(W + (size_t)(k0 + wkk) * N + col0 + wc);
        __syncthreads();
        As[ak+0][ar] = a.x;
        As[ak+1][ar] = a.y;
        As[ak+2][ar] = a.z;
        As[ak+3][ar] = a.w;
        *(float4*)&Ws[wkk][wc] = w;
        __syncthreads();
        #pragma unroll
        for (int kk = 0; kk < 16; ++kk) {
            float4 av = *(const float4*)&As[kk][tr << 2];
            float4 wv = *(const float4*)&Ws[kk][tc << 2];
            float aa[4] = {av.x, av.y, av.z, av.w};
            float ww[4] = {wv.x, wv.y, wv.z, wv.w};
            #pragma unroll
            for (int r = 0; r < 4; ++r)
                #pragma unroll
                for (int c = 0; c < 4; ++c)
                    acc[r][c] = fmaf(aa[r], ww[c], acc[r][c]);
        }
    }

    #pragma unroll
    for (int r = 0; r < 4; ++r) {
        int row = row0 + (tr << 2) + r;
        #pragma unroll
        for (int c = 0; c < 4; ++c) {
            int col = col0 + (tc << 2) + c;
            float v = acc[r][c] + bias[col];
            if (RELU) v = v > 0.f ? v : 0.f;
            if (OUT_BHLD) {
                int b  = row >> 11;       // row / L
                int l  = row & (LL - 1);
                int hh = col >> 5;        // col / 32
                int dh = col & 31;
                C[(((size_t)(b * NH + hh) * LL + l) << 5) + dh] = v;
            } else {
                C[(size_t)row * N + col] = v;
            }
        }
    }
}

__device__ inline float dot32(const float4* a, const float4* k4)
{
    float s = 0.f;
    #pragma unroll
    for (int i = 0; i < 8; ++i) {
        float4 av = a[i], kv = k4[i];
        s = fmaf(av.x, kv.x, s);
        s = fmaf(av.y, kv.y, s);
        s = fmaf(av.z, kv.z, s);
        s = fmaf(av.w, kv.w, s);
    }
    return s;
}

// M[b,h,l] = max_s(q·k_sampled) - sum_s(q·k_sampled)/L
__global__ __launch_bounds__(256)
void metric_k(const float* __restrict__ qb, const float* __restrict__ kb,
              const int* __restrict__ idx, float* __restrict__ Mout)
{
    int tid = blockIdx.x * 256 + threadIdx.x;   // 0 .. B*H*L-1
    int bh  = tid >> 11;
    int l   = tid & (LL - 1);

    float4 q[8];
    const float4* qr = (const float4*)(qb + ((size_t)(bh * LL + l) << 5));
    #pragma unroll
    for (int i = 0; i < 8; ++i) q[i] = qr[i];

    const int* ir = idx + l * SS;
    const float* kbase = kb + ((size_t)bh * LL << 5);
    float mx = -1e30f, sm = 0.f;
    for (int s = 0; s < SS; ++s) {
        const float4* kr = (const float4*)(kbase + ((size_t)ir[s] << 5));
        float d = dot32(q, kr);
        mx = fmaxf(mx, d);
        sm += d;
    }
    Mout[tid] = mx - sm * (1.0f / (float)LL);
}

// per (b,h): indices of top-40 M values (iterative argmax, ties -> lower idx)
__global__ __launch_bounds__(256)
void topk_k(const float* __restrict__ Mbuf, int* __restrict__ top)
{
    __shared__ float vals[LL];
    __shared__ float rv[256];
    __shared__ int   ri[256];
    int bh = blockIdx.x;
    int t  = threadIdx.x;
    const float* src = Mbuf + (size_t)bh * LL;
    for (int i = t; i < LL; i += 256) vals[i] = src[i];
    __syncthreads();
    for (int r = 0; r < UU; ++r) {
        float bv = -1e30f; int bi = 0x7fffffff;
        for (int i = t; i < LL; i += 256) {
            float v = vals[i];
            if (v > bv || (v == bv && i < bi)) { bv = v; bi = i; }
        }
        rv[t] = bv; ri[t] = bi;
        __syncthreads();
        for (int off = 128; off > 0; off >>= 1) {
            if (t < off) {
                float ov = rv[t + off]; int oi = ri[t + off];
                if (ov > rv[t] || (ov == rv[t] && oi < ri[t])) { rv[t] = ov; ri[t] = oi; }
            }
            __syncthreads();
        }
        if (t == 0) { top[bh * UU + r] = ri[0]; vals[ri[0]] = -1e30f; }
        __syncthreads();
    }
}

// vmean[b,h,d] = mean over l of v
__global__ __launch_bounds__(256)
void vmean_k(const float* __restrict__ vb, float* __restrict__ vmean)
{
    __shared__ float red[8][32];
    int bh = blockIdx.x, t = threadIdx.x;
    int d = t & 31, part = t >> 5;
    const float* base = vb + ((size_t)bh * LL << 5);
    float s = 0.f;
    int l0 = part * 256;
    for (int i = 0; i < 256; ++i) s += base[((l0 + i) << 5) + d];
    red[part][d] = s;
    __syncthreads();
    if (t < 32) {
        float tot = 0.f;
        #pragma unroll
        for (int p = 0; p < 8; ++p) tot += red[p][t];
        vmean[bh * 32 + t] = tot * (1.f / (float)LL);
    }
}

// For one (b,h,j): softmax(q_top · K / sqrt(DH)) @ V  -> upd[b,h,j,:]
__global__ __launch_bounds__(256)
void attnupd_k(const float* __restrict__ qb, const float* __restrict__ kb,
               const float* __restrict__ vb, const int* __restrict__ top,
               float* __restrict__ upd)
{
    __shared__ float p[LL];
    __shared__ float red[256];
    __shared__ float redm[8][32];
    __shared__ float inv_s;

    int bh = blockIdx.x / UU;
    int j  = blockIdx.x % UU;
    int t  = threadIdx.x;
    int qi = top[bh * UU + j];

    float4 q[8];
    const float4* qr = (const float4*)(qb + ((size_t)(bh * LL + qi) << 5));
    #pragma unroll
    for (int i = 0; i < 8; ++i) q[i] = qr[i];

    const float* kbase = kb + ((size_t)bh * LL << 5);
    const float* vbase = vb + ((size_t)bh * LL << 5);
    const float scale = 0.17677669529663687f;   // 1/sqrt(32)

    for (int l = t; l < LL; l += 256) {
        const float4* kr = (const float4*)(kbase + ((size_t)l << 5));
        p[l] = dot32(q, kr) * scale;
    }
    __syncthreads();

    // block max
    float mx = -1e30f;
    for (int l = t; l < LL; l += 256) mx = fmaxf(mx, p[l]);
    red[t] = mx;
    __syncthreads();
    for (int off = 128; off > 0; off >>= 1) {
        if (t < off) red[t] = fmaxf(red[t], red[t + off]);
        __syncthreads();
    }
    mx = red[0];
    __syncthreads();

    // exp + block sum
    float sm = 0.f;
    for (int l = t; l < LL; l += 256) {
        float e = expf(p[l] - mx);
        p[l] = e;
        sm += e;
    }
    red[t] = sm;
    __syncthreads();
    for (int off = 128; off > 0; off >>= 1) {
        if (t < off) red[t] += red[t + off];
        __syncthreads();
    }
    if (t == 0) inv_s = 1.0f / red[0];
    __syncthreads();

    // upd[d] = sum_l p[l] * v[l,d]
    int d = t & 31, part = t >> 5;
    float acc = 0.f;
    int l0 = part * 256;
    for (int i = 0; i < 256; ++i) {
        int l = l0 + i;
        acc = fmaf(p[l], vbase[((size_t)l << 5) + d], acc);
    }
    redm[part][d] = acc;
    __syncthreads();
    if (t < 32) {
        float tot = 0.f;
        #pragma unroll
        for (int pp = 0; pp < 8; ++pp) tot += redm[pp][t];
        upd[((size_t)bh * UU + j) * 32 + t] = tot * inv_s;
    }
}

// ctx[b,l,h*32+d] = vmean[b,h,d]  (note vmean for b is contiguous 256 floats)
__global__ __launch_bounds__(256)
void fill_k(float* __restrict__ ctx, const float* __restrict__ vmean)
{
    int tid = blockIdx.x * 256 + threadIdx.x;   // over BL*DM
    int d = tid & 255;
    int b = tid >> 19;                          // tid / (L*DM)
    ctx[tid] = vmean[(b << 8) + d];
}

// ctx[b, top[b,h,j], h*32+d] = upd[b,h,j,d]
__global__ __launch_bounds__(256)
void scatter_k(float* __restrict__ ctx, const float* __restrict__ upd,
               const int* __restrict__ top)
{
    int tid = blockIdx.x * 256 + threadIdx.x;   // over B*H*U*32 = 81920
    int d  = tid & 31;
    int j  = (tid >> 5) % UU;
    int bh = tid / (UU * 32);
    int b  = bh >> 3, hh = bh & 7;
    int qi = top[bh * UU + j];
    ctx[(((size_t)(b * LL + qi)) << 8) + (hh << 5) + d] = upd[tid];
}

// h = LN(h + nx) * g + beta   (one row of 256 per block)
__global__ __launch_bounds__(256)
void addln_k(float* __restrict__ h, const float* __restrict__ nx,
             const float* __restrict__ g, const float* __restrict__ beta)
{
    int row = blockIdx.x, t = threadIdx.x;
    size_t base = (size_t)row * DM + t;
    float x = h[base] + nx[base];
    float s = x, s2 = x * x;
    #pragma unroll
    for (int off = 32; off > 0; off >>= 1) {
        s  += __shfl_down(s, off);
        s2 += __shfl_down(s2, off);
    }
    __shared__ float ws1[4], ws2[4];
    __shared__ float mean_s, inv_s;
    int wave = t >> 6, lane = t & 63;
    if (lane == 0) { ws1[wave] = s; ws2[wave] = s2; }
    __syncthreads();
    if (t == 0) {
        float ts = ws1[0] + ws1[1] + ws1[2] + ws1[3];
        float t2 = ws2[0] + ws2[1] + ws2[2] + ws2[3];
        float m  = ts * (1.f / (float)DM);
        float var = t2 * (1.f / (float)DM) - m * m;
        mean_s = m;
        inv_s  = 1.0f / sqrtf(var + 1e-5f);
    }
    __syncthreads();
    h[base] = (x - mean_s) * inv_s * g[t] + beta[t];
}

// out[b] = relu(h[b,L-1,:] @ w_fc1 + b_fc1) @ w_fc2 + b_fc2
__global__ __launch_bounds__(512)
void head_k(const float* __restrict__ h, const float* __restrict__ w1,
            const float* __restrict__ b1, const float* __restrict__ w2,
            const float* __restrict__ b2, float* __restrict__ out)
{
    int t = threadIdx.x;
    int b = t >> 6, j = t & 63;
    const float* hr = h + ((size_t)(b * LL + (LL - 1))) * DM;
    float s = 0.f;
    for (int kk = 0; kk < DM; ++kk) s = fmaf(hr[kk], w1[kk * 64 + j], s);
    s += b1[j];
    s = s > 0.f ? s : 0.f;
    float contrib = s * w2[j];
    #pragma unroll
    for (int off = 32; off > 0; off >>= 1) contrib += __shfl_down(contrib, off);
    if (j == 0) out[b] = contrib + b2[0];
}

extern "C" void kernel_launch(void* const* d_in, const int* in_sizes, int n_in,
                              void* d_out, int out_size, void* d_ws, size_t ws_size,
                              hipStream_t stream)
{
    const float* x    = (const float*)d_in[0];
    const int*   idx  = (const int*)  d_in[1];
    const float* w_in = (const float*)d_in[2];
    const float* b_in = (const float*)d_in[3];
    const float* wq   = (const float*)d_in[4];
    const float* bq   = (const float*)d_in[5];
    const float* wk   = (const float*)d_in[6];
    const float* bk   = (const float*)d_in[7];
    const float* wv   = (const float*)d_in[8];
    const float* bv   = (const float*)d_in[9];
    const float* wo   = (const float*)d_in[10];
    const float* bo   = (const float*)d_in[11];
    const float* wf1  = (const float*)d_in[12];
    const float* bf1  = (const float*)d_in[13];
    const float* wf2  = (const float*)d_in[14];
    const float* bf2  = (const float*)d_in[15];
    const float* g1   = (const float*)d_in[16];
    const float* be1  = (const float*)d_in[17];
    const float* g2   = (const float*)d_in[18];
    const float* be2  = (const float*)d_in[19];
    const float* wfc1 = (const float*)d_in[20];
    const float* bfc1 = (const float*)d_in[21];
    const float* wfc2 = (const float*)d_in[22];
    const float* bfc2 = (const float*)d_in[23];
    float* out = (float*)d_out;

    float* ws   = (float*)d_ws;
    float* h    = ws;                    // 4,194,304 floats
    float* qb   = ws + 4194304;          // (B,H,L,32)
    float* kb   = ws + 8388608;
    float* vb   = ws + 12582912;
    float* ctx  = ws + 16777216;         // (B*L, 256)
    float* newx = ws + 20971520;
    float* Mbuf = ws + 25165824;         // B*H*L
    float* vme  = ws + 25296896;         // B*H*32
    float* upd  = ws + 25298944;         // B*H*U*32
    int*   top  = (int*)(ws + 25380864); // B*H*U
    float* ffb  = qb;                    // aliases q/k/v/ctx (dead by FF time)

    dim3 blk(256);

    // h = x @ w_in + b_in
    gemm_k<0,0><<<dim3(BL/64, DM/64), blk, 0, stream>>>(x, w_in, b_in, h, BL, DM, 32);

    for (int i = 0; i < 2; ++i) {
        gemm_k<0,1><<<dim3(BL/64, DM/64), blk, 0, stream>>>(h, wq + (size_t)i*DM*DM, bq + i*DM, qb, BL, DM, DM);
        gemm_k<0,1><<<dim3(BL/64, DM/64), blk, 0, stream>>>(h, wk + (size_t)i*DM*DM, bk + i*DM, kb, BL, DM, DM);
        gemm_k<0,1><<<dim3(BL/64, DM/64), blk, 0, stream>>>(h, wv + (size_t)i*DM*DM, bv + i*DM, vb, BL, DM, DM);

        metric_k<<<dim3(BB*NH*LL/256), blk, 0, stream>>>(qb, kb, idx + (size_t)i*LL*SS, Mbuf);
        topk_k<<<dim3(BB*NH), blk, 0, stream>>>(Mbuf, top);
        vmean_k<<<dim3(BB*NH), blk, 0, stream>>>(vb, vme);
        attnupd_k<<<dim3(BB*NH*UU), blk, 0, stream>>>(qb, kb, vb, top, upd);

        fill_k<<<dim3(BL*DM/256), blk, 0, stream>>>(ctx, vme);
        scatter_k<<<dim3(BB*NH*UU*DH/256), blk, 0, stream>>>(ctx, upd, top);

        gemm_k<0,0><<<dim3(BL/64, DM/64), blk, 0, stream>>>(ctx, wo + (size_t)i*DM*DM, bo + i*DM, newx, BL, DM, DM);
        addln_k<<<dim3(BL), blk, 0, stream>>>(h, newx, g1 + i*DM, be1 + i*DM);

        gemm_k<1,0><<<dim3(BL/64, DFF/64), blk, 0, stream>>>(h, wf1 + (size_t)i*DM*DFF, bf1 + i*DFF, ffb, BL, DFF, DM);
        gemm_k<0,0><<<dim3(BL/64, DM/64), blk, 0, stream>>>(ffb, wf2 + (size_t)i*DFF*DM, bf2 + i*DM, newx, BL, DM, DFF);
        addln_k<<<dim3(BL), blk, 0, stream>>>(h, newx, g2 + i*DM, be2 + i*DM);
    }

    head_k<<<dim3(1), dim3(512), 0, stream>>>(h, wfc1, bfc1, wfc2, bfc2, out);
}

// Round 2
// 908.071 us; speedup vs baseline: 1.6530x; 1.6530x over previous
//
#include <hip/hip_runtime.h>
#include <math.h>

#define BB 8
#define LL 2048
#define DM 256
#define NH 8
#define DH 32
#define DFF 1024
#define SS 40
#define UU 40
#define BL (BB*LL)   // 16384

typedef unsigned short ushort_t;
typedef __attribute__((ext_vector_type(8))) short short8;
typedef __attribute__((ext_vector_type(4))) float f32x4;

__device__ inline ushort_t f2b(float f)
{
    unsigned int u = __float_as_uint(f);
    u += 0x7fff + ((u >> 16) & 1);      // round-to-nearest-even
    return (ushort_t)(u >> 16);
}

__device__ inline void gload16(const void* g, const void* l)
{
    __builtin_amdgcn_global_load_lds(
        (const __attribute__((address_space(1))) unsigned int*)g,
        (__attribute__((address_space(3))) unsigned int*)l, 16, 0, 0);
}

// ---------------------------------------------------------------------------
// bf16 MFMA GEMM: C = A(MxK,bf16) @ Bt^T(N x K,bf16) + bias, m97 structure.
// 128x128 tile, BK=32, 256 thr (4 waves), each wave 64x64 via 4x4 MFMA tiles.
// OUT_MODE: 0 = fp32 row-major, 1 = fp32 fused-QKV->(B,H,L,DH)x3, 2 = bf16 RM
// ---------------------------------------------------------------------------
template<int RELU, int OUT_MODE>
__global__ __launch_bounds__(256)
void gemm_mfma(const ushort_t* __restrict__ A, const ushort_t* __restrict__ Bt,
               const float* __restrict__ bias, void* __restrict__ Cout,
               int M, int N, int K)
{
    __shared__ ushort_t Asl[128 * 32];
    __shared__ ushort_t Bsl[128 * 32];

    const int t    = threadIdx.x;
    const int lane = t & 63;
    const int wv   = t >> 6;
    const int row0 = blockIdx.x * 128;
    const int col0 = blockIdx.y * 128;
    const int wr   = (wv >> 1) * 64;
    const int wc   = (wv & 1) * 64;
    const int quad = lane >> 4;
    const int l16  = lane & 15;

    f32x4 acc[4][4];
    #pragma unroll
    for (int i = 0; i < 4; ++i)
        #pragma unroll
        for (int j = 0; j < 4; ++j)
            acc[i][j] = 0.f;

    for (int k0 = 0; k0 < K; k0 += 32) {
        __syncthreads();   // previous iter's LDS reads done
        #pragma unroll
        for (int r = 0; r < 2; ++r) {
            int g = r * 256 + t;
            const ushort_t* ga = A  + (size_t)(row0 + (g >> 2)) * K + k0 + (g & 3) * 8;
            const ushort_t* gb = Bt + (size_t)(col0 + (g >> 2)) * K + k0 + (g & 3) * 8;
            int lbase = (r * 256 + wv * 64) * 16;   // bytes, wave-uniform
            gload16(ga, (const char*)Asl + lbase);
            gload16(gb, (const char*)Bsl + lbase);
        }
        __syncthreads();   // loads landed

        short8 af[4], bfr[4];
        #pragma unroll
        for (int mi = 0; mi < 4; ++mi)
            af[mi] = *(const short8*)&Asl[(wr + mi * 16 + l16) * 32 + quad * 8];
        #pragma unroll
        for (int ni = 0; ni < 4; ++ni)
            bfr[ni] = *(const short8*)&Bsl[(wc + ni * 16 + l16) * 32 + quad * 8];
        #pragma unroll
        for (int mi = 0; mi < 4; ++mi)
            #pragma unroll
            for (int ni = 0; ni < 4; ++ni)
                acc[mi][ni] = __builtin_amdgcn_mfma_f32_16x16x32_bf16(
                    af[mi], bfr[ni], acc[mi][ni], 0, 0, 0);
    }

    #pragma unroll
    for (int mi = 0; mi < 4; ++mi) {
        #pragma unroll
        for (int ni = 0; ni < 4; ++ni) {
            int col = col0 + wc + ni * 16 + l16;
            float bb = bias[col];
            #pragma unroll
            for (int r = 0; r < 4; ++r) {
                int row = row0 + wr + mi * 16 + quad * 4 + r;
                float v = acc[mi][ni][r] + bb;
                if (RELU) v = v > 0.f ? v : 0.f;
                if (OUT_MODE == 0) {
                    ((float*)Cout)[(size_t)row * N + col] = v;
                } else if (OUT_MODE == 1) {
                    int tensor = col >> 8;          // 0=q 1=k 2=v
                    int c2 = col & 255;
                    int b  = row >> 11, l = row & (LL - 1);
                    int hh = c2 >> 5,  dh = c2 & 31;
                    ((float*)Cout)[(size_t)tensor * (BB*NH*LL*DH)
                        + (((size_t)(b * NH + hh) * LL + l) << 5) + dh] = v;
                } else {
                    ((ushort_t*)Cout)[(size_t)row * N + col] = f2b(v);
                }
            }
        }
    }
}

// 32x32-tiled transpose + fp32->bf16: dst[m][n][k] = src[m][k][n]
__global__ __launch_bounds__(256)
void tcvt_k(const float* __restrict__ src, ushort_t* __restrict__ dst,
            int K, int N, int matStride)
{
    __shared__ float tile[32][33];
    int tilesN = N >> 5;
    int tpm = (K >> 5) * tilesN;
    int m   = blockIdx.x / tpm;
    int tid = blockIdx.x % tpm;
    int k0 = (tid / tilesN) << 5, n0 = (tid % tilesN) << 5;
    const float* s = src + (size_t)m * K * N;
    ushort_t*    d = dst + (size_t)m * matStride;
    int r = threadIdx.x >> 5, c = threadIdx.x & 31;
    #pragma unroll
    for (int i = 0; i < 4; ++i)
        tile[r + 8 * i][c] = s[(size_t)(k0 + r + 8 * i) * N + n0 + c];
    __syncthreads();
    #pragma unroll
    for (int i = 0; i < 4; ++i)
        d[(size_t)(n0 + r + 8 * i) * K + k0 + c] = f2b(tile[c][r + 8 * i]);
}

// pack bq|bk|bv -> (2,768)
__global__ __launch_bounds__(256)
void bpack_k(const float* __restrict__ bq, const float* __restrict__ bk,
             const float* __restrict__ bv, float* __restrict__ dst)
{
    int t = blockIdx.x * 256 + threadIdx.x;   // 0..1535
    int i = t / 768, j = t % 768;
    const float* s = j < 256 ? bq : (j < 512 ? bk : bv);
    dst[t] = s[i * 256 + (j & 255)];
}

// fp32 GEMM (only w_in, K=32), also emits bf16 copy of output
__global__ __launch_bounds__(256)
void gemm_k(const float* __restrict__ A, const float* __restrict__ W,
            const float* __restrict__ bias, float* __restrict__ C,
            ushort_t* __restrict__ hbout, int M, int N, int K)
{
    __shared__ float As[16][68];
    __shared__ float Ws[16][64];
    const int t    = threadIdx.x;
    const int row0 = blockIdx.x * 64;
    const int col0 = blockIdx.y * 64;
    const int ar  = t >> 2;
    const int ak  = (t & 3) << 2;
    const int wkk = t >> 4;
    const int wc  = (t & 15) << 2;
    const int tr  = t >> 4;
    const int tc  = t & 15;

    float acc[4][4] = {{0.f,0.f,0.f,0.f},{0.f,0.f,0.f,0.f},
                       {0.f,0.f,0.f,0.f},{0.f,0.f,0.f,0.f}};

    for (int k0 = 0; k0 < K; k0 += 16) {
        float4 a = *(const float4*)(A + (size_t)(row0 + ar) * K + k0 + ak);
        float4 w = *(const float4*)(W + (size_t)(k0 + wkk) * N + col0 + wc);
        __syncthreads();
        As[ak+0][ar] = a.x; As[ak+1][ar] = a.y;
        As[ak+2][ar] = a.z; As[ak+3][ar] = a.w;
        *(float4*)&Ws[wkk][wc] = w;
        __syncthreads();
        #pragma unroll
        for (int kk = 0; kk < 16; ++kk) {
            float4 av = *(const float4*)&As[kk][tr << 2];
            float4 wv4 = *(const float4*)&Ws[kk][tc << 2];
            float aa[4] = {av.x, av.y, av.z, av.w};
            float ww[4] = {wv4.x, wv4.y, wv4.z, wv4.w};
            #pragma unroll
            for (int r = 0; r < 4; ++r)
                #pragma unroll
                for (int c = 0; c < 4; ++c)
                    acc[r][c] = fmaf(aa[r], ww[c], acc[r][c]);
        }
    }
    #pragma unroll
    for (int r = 0; r < 4; ++r) {
        int row = row0 + (tr << 2) + r;
        #pragma unroll
        for (int c = 0; c < 4; ++c) {
            int col = col0 + (tc << 2) + c;
            float v = acc[r][c] + bias[col];
            C[(size_t)row * N + col] = v;
            hbout[(size_t)row * N + col] = f2b(v);
        }
    }
}

__device__ inline float dot32(const float4* a, const float4* k4)
{
    float s = 0.f;
    #pragma unroll
    for (int i = 0; i < 8; ++i) {
        float4 av = a[i], kv = k4[i];
        s = fmaf(av.x, kv.x, s);
        s = fmaf(av.y, kv.y, s);
        s = fmaf(av.z, kv.z, s);
        s = fmaf(av.w, kv.w, s);
    }
    return s;
}

__global__ __launch_bounds__(256)
void metric_k(const float* __restrict__ qb, const float* __restrict__ kb,
              const int* __restrict__ idx, float* __restrict__ Mout)
{
    int tid = blockIdx.x * 256 + threadIdx.x;
    int bh  = tid >> 11;
    int l   = tid & (LL - 1);
    float4 q[8];
    const float4* qr = (const float4*)(qb + ((size_t)(bh * LL + l) << 5));
    #pragma unroll
    for (int i = 0; i < 8; ++i) q[i] = qr[i];
    const int* ir = idx + l * SS;
    const float* kbase = kb + ((size_t)bh * LL << 5);
    float mx = -1e30f, sm = 0.f;
    for (int s = 0; s < SS; ++s) {
        const float4* kr = (const float4*)(kbase + ((size_t)ir[s] << 5));
        float d = dot32(q, kr);
        mx = fmaxf(mx, d);
        sm += d;
    }
    Mout[tid] = mx - sm * (1.0f / (float)LL);
}

__global__ __launch_bounds__(256)
void topk_k(const float* __restrict__ Mbuf, int* __restrict__ top)
{
    __shared__ float vals[LL];
    __shared__ float rv[256];
    __shared__ int   ri[256];
    int bh = blockIdx.x;
    int t  = threadIdx.x;
    const float* src = Mbuf + (size_t)bh * LL;
    for (int i = t; i < LL; i += 256) vals[i] = src[i];
    __syncthreads();
    for (int r = 0; r < UU; ++r) {
        float bv = -1e30f; int bi = 0x7fffffff;
        for (int i = t; i < LL; i += 256) {
            float v = vals[i];
            if (v > bv || (v == bv && i < bi)) { bv = v; bi = i; }
        }
        rv[t] = bv; ri[t] = bi;
        __syncthreads();
        for (int off = 128; off > 0; off >>= 1) {
            if (t < off) {
                float ov = rv[t + off]; int oi = ri[t + off];
                if (ov > rv[t] || (ov == rv[t] && oi < ri[t])) { rv[t] = ov; ri[t] = oi; }
            }
            __syncthreads();
        }
        if (t == 0) { top[bh * UU + r] = ri[0]; vals[ri[0]] = -1e30f; }
        __syncthreads();
    }
}

__global__ __launch_bounds__(256)
void vmean_k(const float* __restrict__ vb, float* __restrict__ vmean)
{
    __shared__ float red[8][32];
    int bh = blockIdx.x, t = threadIdx.x;
    int d = t & 31, part = t >> 5;
    const float* base = vb + ((size_t)bh * LL << 5);
    float s = 0.f;
    int l0 = part * 256;
    for (int i = 0; i < 256; ++i) s += base[((l0 + i) << 5) + d];
    red[part][d] = s;
    __syncthreads();
    if (t < 32) {
        float tot = 0.f;
        #pragma unroll
        for (int p = 0; p < 8; ++p) tot += red[p][t];
        vmean[bh * 32 + t] = tot * (1.f / (float)LL);
    }
}

__global__ __launch_bounds__(256)
void attnupd_k(const float* __restrict__ qb, const float* __restrict__ kb,
               const float* __restrict__ vb, const int* __restrict__ top,
               float* __restrict__ upd)
{
    __shared__ float p[LL];
    __shared__ float red[256];
    __shared__ float redm[8][32];
    __shared__ float inv_s;

    int bh = blockIdx.x / UU;
    int j  = blockIdx.x % UU;
    int t  = threadIdx.x;
    int qi = top[bh * UU + j];

    float4 q[8];
    const float4* qr = (const float4*)(qb + ((size_t)(bh * LL + qi) << 5));
    #pragma unroll
    for (int i = 0; i < 8; ++i) q[i] = qr[i];

    const float* kbase = kb + ((size_t)bh * LL << 5);
    const float* vbase = vb + ((size_t)bh * LL << 5);
    const float scale = 0.17677669529663687f;

    for (int l = t; l < LL; l += 256) {
        const float4* kr = (const float4*)(kbase + ((size_t)l << 5));
        p[l] = dot32(q, kr) * scale;
    }
    __syncthreads();
    float mx = -1e30f;
    for (int l = t; l < LL; l += 256) mx = fmaxf(mx, p[l]);
    red[t] = mx;
    __syncthreads();
    for (int off = 128; off > 0; off >>= 1) {
        if (t < off) red[t] = fmaxf(red[t], red[t + off]);
        __syncthreads();
    }
    mx = red[0];
    __syncthreads();
    float sm = 0.f;
    for (int l = t; l < LL; l += 256) {
        float e = expf(p[l] - mx);
        p[l] = e;
        sm += e;
    }
    red[t] = sm;
    __syncthreads();
    for (int off = 128; off > 0; off >>= 1) {
        if (t < off) red[t] += red[t + off];
        __syncthreads();
    }
    if (t == 0) inv_s = 1.0f / red[0];
    __syncthreads();

    int d = t & 31, part = t >> 5;
    float acc = 0.f;
    int l0 = part * 256;
    for (int i = 0; i < 256; ++i) {
        int l = l0 + i;
        acc = fmaf(p[l], vbase[((size_t)l << 5) + d], acc);
    }
    redm[part][d] = acc;
    __syncthreads();
    if (t < 32) {
        float tot = 0.f;
        #pragma unroll
        for (int pp = 0; pp < 8; ++pp) tot += redm[pp][t];
        upd[((size_t)bh * UU + j) * 32 + t] = tot * inv_s;
    }
}

// ctx (bf16)[b,l,h*32+d] = vmean[b,h,d]
__global__ __launch_bounds__(256)
void fill_k(ushort_t* __restrict__ ctxb, const float* __restrict__ vmean)
{
    int tid = blockIdx.x * 256 + threadIdx.x;
    int d = tid & 255;
    int b = tid >> 19;
    ctxb[tid] = f2b(vmean[(b << 8) + d]);
}

__global__ __launch_bounds__(256)
void scatter_k(ushort_t* __restrict__ ctxb, const float* __restrict__ upd,
               const int* __restrict__ top)
{
    int tid = blockIdx.x * 256 + threadIdx.x;
    int d  = tid & 31;
    int j  = (tid >> 5) % UU;
    int bh = tid / (UU * 32);
    int b  = bh >> 3, hh = bh & 7;
    int qi = top[bh * UU + j];
    ctxb[(((size_t)(b * LL + qi)) << 8) + (hh << 5) + d] = f2b(upd[tid]);
}

// h = LN(h + nx)*g + beta ; also writes bf16 copy
__global__ __launch_bounds__(256)
void addln_k(float* __restrict__ h, ushort_t* __restrict__ hb,
             const float* __restrict__ nx,
             const float* __restrict__ g, const float* __restrict__ beta)
{
    int row = blockIdx.x, t = threadIdx.x;
    size_t base = (size_t)row * DM + t;
    float x = h[base] + nx[base];
    float s = x, s2 = x * x;
    #pragma unroll
    for (int off = 32; off > 0; off >>= 1) {
        s  += __shfl_down(s, off);
        s2 += __shfl_down(s2, off);
    }
    __shared__ float ws1[4], ws2[4];
    __shared__ float mean_s, inv_s;
    int wave = t >> 6, lane = t & 63;
    if (lane == 0) { ws1[wave] = s; ws2[wave] = s2; }
    __syncthreads();
    if (t == 0) {
        float ts = ws1[0] + ws1[1] + ws1[2] + ws1[3];
        float t2 = ws2[0] + ws2[1] + ws2[2] + ws2[3];
        float m  = ts * (1.f / (float)DM);
        float var = t2 * (1.f / (float)DM) - m * m;
        mean_s = m;
        inv_s  = 1.0f / sqrtf(var + 1e-5f);
    }
    __syncthreads();
    float res = (x - mean_s) * inv_s * g[t] + beta[t];
    h[base]  = res;
    hb[base] = f2b(res);
}

__global__ __launch_bounds__(512)
void head_k(const float* __restrict__ h, const float* __restrict__ w1,
            const float* __restrict__ b1, const float* __restrict__ w2,
            const float* __restrict__ b2, float* __restrict__ out)
{
    int t = threadIdx.x;
    int b = t >> 6, j = t & 63;
    const float* hr = h + ((size_t)(b * LL + (LL - 1))) * DM;
    float s = 0.f;
    for (int kk = 0; kk < DM; ++kk) s = fmaf(hr[kk], w1[kk * 64 + j], s);
    s += b1[j];
    s = s > 0.f ? s : 0.f;
    float contrib = s * w2[j];
    #pragma unroll
    for (int off = 32; off > 0; off >>= 1) contrib += __shfl_down(contrib, off);
    if (j == 0) out[b] = contrib + b2[0];
}

extern "C" void kernel_launch(void* const* d_in, const int* in_sizes, int n_in,
                              void* d_out, int out_size, void* d_ws, size_t ws_size,
                              hipStream_t stream)
{
    const float* x    = (const float*)d_in[0];
    const int*   idx  = (const int*)  d_in[1];
    const float* w_in = (const float*)d_in[2];
    const float* b_in = (const float*)d_in[3];
    const float* wq   = (const float*)d_in[4];
    const float* bq   = (const float*)d_in[5];
    const float* wk   = (const float*)d_in[6];
    const float* bk   = (const float*)d_in[7];
    const float* wv   = (const float*)d_in[8];
    const float* bv   = (const float*)d_in[9];
    const float* wo   = (const float*)d_in[10];
    const float* bo   = (const float*)d_in[11];
    const float* wf1  = (const float*)d_in[12];
    const float* bf1  = (const float*)d_in[13];
    const float* wf2  = (const float*)d_in[14];
    const float* bf2  = (const float*)d_in[15];
    const float* g1   = (const float*)d_in[16];
    const float* be1  = (const float*)d_in[17];
    const float* g2   = (const float*)d_in[18];
    const float* be2  = (const float*)d_in[19];
    const float* wfc1 = (const float*)d_in[20];
    const float* bfc1 = (const float*)d_in[21];
    const float* wfc2 = (const float*)d_in[22];
    const float* bfc2 = (const float*)d_in[23];
    float* out = (float*)d_out;

    float* ws = (float*)d_ws;
    float*    h     = ws;                          // 4194304
    float*    qkv   = ws + 4194304;                // 12582912 (q,k,v)
    float*    qb    = qkv;
    float*    kb    = qkv + 4194304;
    float*    vb    = qkv + 8388608;
    float*    newx  = ws + 16777216;               // 4194304
    float*    Mbuf  = ws + 20971520;               // 131072
    float*    vme   = ws + 21102592;               // 2048
    float*    upd   = ws + 21104640;               // 81920
    int*      top   = (int*)(ws + 21186560);       // 2560
    ushort_t* hb    = (ushort_t*)(ws + 21190656);  // 4194304 ushorts
    ushort_t* wqkvT = (ushort_t*)(ws + 23287808);  // 2x768x256
    ushort_t* woT   = (ushort_t*)(ws + 23484416);  // 2x256x256
    ushort_t* wf1T  = (ushort_t*)(ws + 23549952);  // 2x1024x256
    ushort_t* wf2T  = (ushort_t*)(ws + 23812096);  // 2x256x1024
    float*    bqkv  = ws + 24074240;               // 1536
    ushort_t* ctxb  = (ushort_t*)qkv;              // aliases dead q
    ushort_t* ffbb  = (ushort_t*)(qkv + 2097152);  // aliases dead k/v

    dim3 blk(256);

    // weight convert+transpose (per call; inputs are restored each launch)
    tcvt_k<<<dim3(2*64),  blk, 0, stream>>>(wq,  wqkvT,           DM, DM,  768*256);
    tcvt_k<<<dim3(2*64),  blk, 0, stream>>>(wk,  wqkvT + 256*256, DM, DM,  768*256);
    tcvt_k<<<dim3(2*64),  blk, 0, stream>>>(wv,  wqkvT + 512*256, DM, DM,  768*256);
    tcvt_k<<<dim3(2*64),  blk, 0, stream>>>(wo,  woT,             DM, DM,  256*256);
    tcvt_k<<<dim3(2*256), blk, 0, stream>>>(wf1, wf1T,            DM, DFF, 1024*256);
    tcvt_k<<<dim3(2*256), blk, 0, stream>>>(wf2, wf2T,            DFF, DM, 256*1024);
    bpack_k<<<dim3(6), blk, 0, stream>>>(bq, bk, bv, bqkv);

    // h = x @ w_in + b_in (fp32, K=32) + bf16 shadow
    gemm_k<<<dim3(BL/64, DM/64), blk, 0, stream>>>(x, w_in, b_in, h, hb, BL, DM, 32);

    for (int i = 0; i < 2; ++i) {
        // fused QKV: (16384x256) @ (256x768)
        gemm_mfma<0,1><<<dim3(BL/128, 6), blk, 0, stream>>>(
            hb, wqkvT + (size_t)i*768*256, bqkv + i*768, (void*)qkv, BL, 768, DM);

        metric_k<<<dim3(BB*NH*LL/256), blk, 0, stream>>>(qb, kb, idx + (size_t)i*LL*SS, Mbuf);
        topk_k<<<dim3(BB*NH), blk, 0, stream>>>(Mbuf, top);
        vmean_k<<<dim3(BB*NH), blk, 0, stream>>>(vb, vme);
        attnupd_k<<<dim3(BB*NH*UU), blk, 0, stream>>>(qb, kb, vb, top, upd);

        fill_k<<<dim3(BL*DM/256), blk, 0, stream>>>(ctxb, vme);
        scatter_k<<<dim3(BB*NH*UU*DH/256), blk, 0, stream>>>(ctxb, upd, top);

        gemm_mfma<0,0><<<dim3(BL/128, 2), blk, 0, stream>>>(
            ctxb, woT + (size_t)i*256*256, bo + i*DM, (void*)newx, BL, DM, DM);
        addln_k<<<dim3(BL), blk, 0, stream>>>(h, hb, newx, g1 + i*DM, be1 + i*DM);

        gemm_mfma<1,2><<<dim3(BL/128, 8), blk, 0, stream>>>(
            hb, wf1T + (size_t)i*1024*256, bf1 + i*DFF, (void*)ffbb, BL, DFF, DM);
        gemm_mfma<0,0><<<dim3(BL/128, 2), blk, 0, stream>>>(
            ffbb, wf2T + (size_t)i*256*1024, bf2 + i*DM, (void*)newx, BL, DM, DFF);
        addln_k<<<dim3(BL), blk, 0, stream>>>(h, hb, newx, g2 + i*DM, be2 + i*DM);
    }

    head_k<<<dim3(1), dim3(512), 0, stream>>>(h, wfc1, bfc1, wfc2, bfc2, out);
}

// Round 3
// 656.054 us; speedup vs baseline: 2.2880x; 1.3841x over previous
//
#include <hip/hip_runtime.h>
#include <math.h>

#define BB 8
#define LL 2048
#define DM 256
#define NH 8
#define DH 32
#define DFF 1024
#define SS 40
#define UU 40
#define BL (BB*LL)   // 16384

typedef unsigned short ushort_t;
typedef __attribute__((ext_vector_type(8))) short short8;
typedef __attribute__((ext_vector_type(4))) float f32x4;

__device__ inline ushort_t f2b(float f)
{
    unsigned int u = __float_as_uint(f);
    u += 0x7fff + ((u >> 16) & 1);      // round-to-nearest-even
    return (ushort_t)(u >> 16);
}

__device__ inline void gload16(const void* g, const void* l)
{
    __builtin_amdgcn_global_load_lds(
        (const __attribute__((address_space(1))) unsigned int*)g,
        (__attribute__((address_space(3))) unsigned int*)l, 16, 0, 0);
}

// ---------------------------------------------------------------------------
// bf16 MFMA GEMM, m97 structure. 128x128 tile, BK=32, 256 thr.
// OUT_MODE: 0 fp32 RM | 1 QKV scatter (fp32 q,k,v + bf16 k into aux)
//           2 bf16 RM | 3 fp32 RM + bf16 RM into aux
// ---------------------------------------------------------------------------
template<int RELU, int OUT_MODE>
__global__ __launch_bounds__(256)
void gemm_mfma(const ushort_t* __restrict__ A, const ushort_t* __restrict__ Bt,
               const float* __restrict__ bias, void* __restrict__ Cout,
               void* __restrict__ aux, int M, int N, int K)
{
    __shared__ ushort_t Asl[128 * 32];
    __shared__ ushort_t Bsl[128 * 32];

    const int t    = threadIdx.x;
    const int lane = t & 63;
    const int wv   = t >> 6;
    const int row0 = blockIdx.x * 128;
    const int col0 = blockIdx.y * 128;
    const int wr   = (wv >> 1) * 64;
    const int wc   = (wv & 1) * 64;
    const int quad = lane >> 4;
    const int l16  = lane & 15;

    f32x4 acc[4][4];
    #pragma unroll
    for (int i = 0; i < 4; ++i)
        #pragma unroll
        for (int j = 0; j < 4; ++j)
            acc[i][j] = 0.f;

    for (int k0 = 0; k0 < K; k0 += 32) {
        __syncthreads();
        #pragma unroll
        for (int r = 0; r < 2; ++r) {
            int g = r * 256 + t;
            const ushort_t* ga = A  + (size_t)(row0 + (g >> 2)) * K + k0 + (g & 3) * 8;
            const ushort_t* gb = Bt + (size_t)(col0 + (g >> 2)) * K + k0 + (g & 3) * 8;
            int lbase = (r * 256 + wv * 64) * 16;
            gload16(ga, (const char*)Asl + lbase);
            gload16(gb, (const char*)Bsl + lbase);
        }
        __syncthreads();

        short8 af[4], bfr[4];
        #pragma unroll
        for (int mi = 0; mi < 4; ++mi)
            af[mi] = *(const short8*)&Asl[(wr + mi * 16 + l16) * 32 + quad * 8];
        #pragma unroll
        for (int ni = 0; ni < 4; ++ni)
            bfr[ni] = *(const short8*)&Bsl[(wc + ni * 16 + l16) * 32 + quad * 8];
        #pragma unroll
        for (int mi = 0; mi < 4; ++mi)
            #pragma unroll
            for (int ni = 0; ni < 4; ++ni)
                acc[mi][ni] = __builtin_amdgcn_mfma_f32_16x16x32_bf16(
                    af[mi], bfr[ni], acc[mi][ni], 0, 0, 0);
    }

    #pragma unroll
    for (int mi = 0; mi < 4; ++mi) {
        #pragma unroll
        for (int ni = 0; ni < 4; ++ni) {
            int col = col0 + wc + ni * 16 + l16;
            float bb = bias[col];
            #pragma unroll
            for (int r = 0; r < 4; ++r) {
                int row = row0 + wr + mi * 16 + quad * 4 + r;
                float v = acc[mi][ni][r] + bb;
                if (RELU) v = v > 0.f ? v : 0.f;
                if (OUT_MODE == 0) {
                    ((float*)Cout)[(size_t)row * N + col] = v;
                } else if (OUT_MODE == 1) {
                    int tensor = col >> 8;          // 0=q 1=k 2=v
                    int c2 = col & 255;
                    int b  = row >> 11, l = row & (LL - 1);
                    int hh = c2 >> 5,  dh = c2 & 31;
                    size_t bi = (((size_t)(b * NH + hh) * LL + l) << 5) + dh;
                    ((float*)Cout)[(size_t)tensor * (BB*NH*LL*DH) + bi] = v;
                    if (tensor == 1) ((ushort_t*)aux)[bi] = f2b(v);
                } else if (OUT_MODE == 2) {
                    ((ushort_t*)Cout)[(size_t)row * N + col] = f2b(v);
                } else {
                    ((float*)Cout)[(size_t)row * N + col] = v;
                    ((ushort_t*)aux)[(size_t)row * N + col] = f2b(v);
                }
            }
        }
    }
}

// 32x32-tiled transpose + fp32->bf16: dst[m][n][k] = src[m][k][n]
__global__ __launch_bounds__(256)
void tcvt_k(const float* __restrict__ src, ushort_t* __restrict__ dst,
            int K, int N, int matStride)
{
    __shared__ float tile[32][33];
    int tilesN = N >> 5;
    int tpm = (K >> 5) * tilesN;
    int m   = blockIdx.x / tpm;
    int tid = blockIdx.x % tpm;
    int k0 = (tid / tilesN) << 5, n0 = (tid % tilesN) << 5;
    const float* s = src + (size_t)m * K * N;
    ushort_t*    d = dst + (size_t)m * matStride;
    int r = threadIdx.x >> 5, c = threadIdx.x & 31;
    #pragma unroll
    for (int i = 0; i < 4; ++i)
        tile[r + 8 * i][c] = s[(size_t)(k0 + r + 8 * i) * N + n0 + c];
    __syncthreads();
    #pragma unroll
    for (int i = 0; i < 4; ++i)
        d[(size_t)(n0 + r + 8 * i) * K + k0 + c] = f2b(tile[c][r + 8 * i]);
}

// pack bq|bk|bv -> (2,768)
__global__ __launch_bounds__(256)
void bpack_k(const float* __restrict__ bq, const float* __restrict__ bk,
             const float* __restrict__ bv, float* __restrict__ dst)
{
    int t = blockIdx.x * 256 + threadIdx.x;
    int i = t / 768, j = t % 768;
    const float* s = j < 256 ? bq : (j < 512 ? bk : bv);
    dst[t] = s[i * 256 + (j & 255)];
}

// x (fp32) -> bf16, vectorized
__global__ __launch_bounds__(256)
void xcvt_k(const float* __restrict__ x, ushort_t* __restrict__ xb)
{
    int tid = blockIdx.x * 256 + threadIdx.x;   // over 131072 float4s
    float4 v = ((const float4*)x)[tid];
    unsigned int lo = f2b(v.x) | ((unsigned int)f2b(v.y) << 16);
    unsigned int hi = f2b(v.z) | ((unsigned int)f2b(v.w) << 16);
    ((uint2*)xb)[tid] = make_uint2(lo, hi);
}

// ---------------------------------------------------------------------------
// metric partials: block = ((bh*4 + sch)*8 + lc); 10 sampled dots per thread
// pm/ps[(sch*64 + bh)*LL + l]
// ---------------------------------------------------------------------------
__global__ __launch_bounds__(256)
void metric_k(const float* __restrict__ qb, const ushort_t* __restrict__ kb16,
              const int* __restrict__ idx, float* __restrict__ pm,
              float* __restrict__ ps)
{
    int blk = blockIdx.x;
    int lc  = blk & 7;
    int sch = (blk >> 3) & 3;
    int bh  = blk >> 5;
    int t   = threadIdx.x;
    int l   = lc * 256 + t;

    float4 q[8];
    const float4* qr = (const float4*)(qb + ((size_t)(bh * LL + l) << 5));
    #pragma unroll
    for (int i = 0; i < 8; ++i) q[i] = qr[i];

    const int* ir = idx + l * SS + sch * 10;
    const uint4* kbase = (const uint4*)(kb16 + ((size_t)bh * LL << 5));

    float mx = -3e38f, sm = 0.f;
    for (int s = 0; s < 10; ++s) {
        int r = ir[s];
        const uint4* kr = kbase + ((size_t)r << 2);   // 4 uint4 per 32-elem row
        float d = 0.f;
        #pragma unroll
        for (int w = 0; w < 4; ++w) {
            uint4 kv = kr[w];
            float4 qa = q[2 * w], qb2 = q[2 * w + 1];
            d = fmaf(__uint_as_float(kv.x << 16),        qa.x, d);
            d = fmaf(__uint_as_float(kv.x & 0xffff0000u), qa.y, d);
            d = fmaf(__uint_as_float(kv.y << 16),        qa.z, d);
            d = fmaf(__uint_as_float(kv.y & 0xffff0000u), qa.w, d);
            d = fmaf(__uint_as_float(kv.z << 16),        qb2.x, d);
            d = fmaf(__uint_as_float(kv.z & 0xffff0000u), qb2.y, d);
            d = fmaf(__uint_as_float(kv.w << 16),        qb2.z, d);
            d = fmaf(__uint_as_float(kv.w & 0xffff0000u), qb2.w, d);
        }
        mx = fmaxf(mx, d);
        sm += d;
    }
    pm[(size_t)(sch * 64 + bh) * LL + l] = mx;
    ps[(size_t)(sch * 64 + bh) * LL + l] = sm;
}

// per (b,h): combine metric partials, then top-40 via wave-shuffle argmax
__global__ __launch_bounds__(256)
void topk_k(const float* __restrict__ pm, const float* __restrict__ ps,
            int* __restrict__ top)
{
    __shared__ float vals[LL];
    __shared__ float rv[4];
    __shared__ int   ri[4];
    int bh = blockIdx.x;
    int t  = threadIdx.x;
    for (int i = t; i < LL; i += 256) {
        float m = -3e38f, s = 0.f;
        #pragma unroll
        for (int sch = 0; sch < 4; ++sch) {
            m = fmaxf(m, pm[(size_t)(sch * 64 + bh) * LL + i]);
            s += ps[(size_t)(sch * 64 + bh) * LL + i];
        }
        vals[i] = m - s * (1.0f / (float)LL);
    }
    __syncthreads();
    int lane = t & 63, wvi = t >> 6;
    for (int r = 0; r < UU; ++r) {
        float bv = -3e38f; int bi = 1 << 30;
        for (int i = t; i < LL; i += 256) {
            float v = vals[i];
            if (v > bv) { bv = v; bi = i; }
        }
        #pragma unroll
        for (int off = 32; off > 0; off >>= 1) {
            float ov = __shfl_down(bv, off, 64);
            int   oi = __shfl_down(bi, off, 64);
            if (ov > bv || (ov == bv && oi < bi)) { bv = ov; bi = oi; }
        }
        if (lane == 0) { rv[wvi] = bv; ri[wvi] = bi; }
        __syncthreads();
        if (t == 0) {
            float fv = rv[0]; int fi = ri[0];
            #pragma unroll
            for (int w = 1; w < 4; ++w)
                if (rv[w] > fv || (rv[w] == fv && ri[w] < fi)) { fv = rv[w]; fi = ri[w]; }
            top[bh * UU + r] = fi;
            vals[fi] = -3e38f;
        }
        __syncthreads();
    }
}

__global__ __launch_bounds__(256)
void vmean_k(const float* __restrict__ vb, float* __restrict__ vmean)
{
    __shared__ float red[8][32];
    int bh = blockIdx.x, t = threadIdx.x;
    int d = t & 31, part = t >> 5;
    const float* base = vb + ((size_t)bh * LL << 5);
    float s = 0.f;
    int l0 = part * 256;
    for (int i = 0; i < 256; ++i) s += base[((l0 + i) << 5) + d];
    red[part][d] = s;
    __syncthreads();
    if (t < 32) {
        float tot = 0.f;
        #pragma unroll
        for (int p = 0; p < 8; ++p) tot += red[p][t];
        vmean[bh * 32 + t] = tot * (1.f / (float)LL);
    }
}

// ---------------------------------------------------------------------------
// attnupd v2: block = bh*4 + quarter. Online softmax over 2 chunks of 256 l,
// j processed in 5 groups of 8. Writes partials mP/sP/OP.
// ---------------------------------------------------------------------------
__global__ __launch_bounds__(256)
void attnupd_k(const float* __restrict__ qb, const float* __restrict__ kb,
               const float* __restrict__ vb, const int* __restrict__ top,
               float* __restrict__ mP, float* __restrict__ sP,
               float* __restrict__ OP)
{
    __shared__ float qs[UU * 32];        // 5 KB
    __shared__ float sc[8 * 256];        // 8 KB
    __shared__ float vs[256 * 36];       // 36.9 KB (pad 36 for b128-aligned rows)
    __shared__ float msh[8];

    int blk = blockIdx.x;
    int qt  = blk & 3;
    int bh  = blk >> 2;
    int t   = threadIdx.x;
    int j8  = t >> 5, d = t & 31;

    for (int i = t; i < UU * 32; i += 256) {
        int j = i >> 5, dd = i & 31;
        int qi = top[bh * UU + j];
        qs[i] = qb[((size_t)(bh * LL + qi) << 5) + dd];
    }

    float m_run[5], S_run[5], acc[5];
    #pragma unroll
    for (int g = 0; g < 5; ++g) { m_run[g] = -3e38f; S_run[g] = 0.f; acc[g] = 0.f; }

    const float scale = 0.17677669529663687f;   // 1/sqrt(32)
    __syncthreads();

    for (int ch = 0; ch < 2; ++ch) {
        int l = qt * 512 + ch * 256 + t;
        const float4* kr = (const float4*)(kb + ((size_t)(bh * LL + l) << 5));
        float4 k4[8];
        #pragma unroll
        for (int i = 0; i < 8; ++i) k4[i] = kr[i];
        const float4* vr = (const float4*)(vb + ((size_t)(bh * LL + l) << 5));
        #pragma unroll
        for (int i = 0; i < 8; ++i) *(float4*)&vs[t * 36 + 4 * i] = vr[i];
        __syncthreads();   // vs staged, prev chunk fully consumed

        for (int g = 0; g < 5; ++g) {
            // scores for j = g*8 + (0..7)
            #pragma unroll
            for (int jj = 0; jj < 8; ++jj) {
                int j = g * 8 + jj;
                float ds = 0.f;
                #pragma unroll
                for (int i = 0; i < 8; ++i) {
                    float4 qv = *(const float4*)&qs[j * 32 + 4 * i];
                    ds = fmaf(qv.x, k4[i].x, ds);
                    ds = fmaf(qv.y, k4[i].y, ds);
                    ds = fmaf(qv.z, k4[i].z, ds);
                    ds = fmaf(qv.w, k4[i].w, ds);
                }
                sc[jj * 256 + t] = ds * scale;
            }
            __syncthreads();

            // chunk max for my j8 (strided + wave shuffle within 32-group)
            float cm = -3e38f;
            #pragma unroll
            for (int ii = 0; ii < 8; ++ii)
                cm = fmaxf(cm, sc[j8 * 256 + d + 32 * ii]);
            #pragma unroll
            for (int off = 16; off > 0; off >>= 1)
                cm = fmaxf(cm, __shfl_down(cm, off, 64));
            cm = __shfl(cm, ((t & 63) >> 5) << 5, 64);

            float m_new = fmaxf(m_run[g], cm);
            float alpha = __expf(m_run[g] - m_new);
            m_run[g] = m_new;
            if (d == 0) msh[j8] = m_new;
            __syncthreads();

            // exp pass (8 entries per thread)
            for (int i = t; i < 2048; i += 256) {
                int jj = i >> 8;
                sc[i] = __expf(sc[i] - msh[jj]);
            }
            __syncthreads();

            // PV + sum
            float ac = acc[g] * alpha;
            float ss = 0.f;
            for (int li = 0; li < 256; ++li) {
                float e = sc[j8 * 256 + li];
                ac = fmaf(e, vs[li * 36 + d], ac);
                ss += e;
            }
            acc[g] = ac;
            S_run[g] = S_run[g] * alpha + ss;
            __syncthreads();   // before next group's score writes
        }
    }

    int pq = bh * 4 + qt;
    #pragma unroll
    for (int g = 0; g < 5; ++g) {
        int j = g * 8 + j8;
        OP[((size_t)pq * UU + j) * 32 + d] = acc[g];
        if (d == 0) {
            sP[pq * UU + j] = S_run[g];
            mP[pq * UU + j] = m_run[g];
        }
    }
}

// merge 4 quarter-partials, normalize, scatter bf16 into ctx
__global__ __launch_bounds__(256)
void combine_k(const float* __restrict__ mP, const float* __restrict__ sP,
               const float* __restrict__ OP, const int* __restrict__ top,
               ushort_t* __restrict__ ctxb)
{
    int tid = blockIdx.x * 256 + threadIdx.x;   // < 64*40*32
    int d  = tid & 31;
    int j  = (tid >> 5) % UU;
    int bh = tid / (UU * 32);
    float M = -3e38f;
    #pragma unroll
    for (int q = 0; q < 4; ++q) M = fmaxf(M, mP[(bh * 4 + q) * UU + j]);
    float S = 0.f, O = 0.f;
    #pragma unroll
    for (int q = 0; q < 4; ++q) {
        float w = __expf(mP[(bh * 4 + q) * UU + j] - M);
        S = fmaf(sP[(bh * 4 + q) * UU + j], w, S);
        O = fmaf(OP[((size_t)(bh * 4 + q) * UU + j) * 32 + d], w, O);
    }
    float u = O / S;
    int qi = top[bh * UU + j];
    int b = bh >> 3, hh = bh & 7;
    ctxb[(((size_t)(b * LL + qi)) << 8) + (hh << 5) + d] = f2b(u);
}

// ctx bf16 fill with vmean broadcast (2 elems/thread packed)
__global__ __launch_bounds__(256)
void fill2_k(ushort_t* __restrict__ ctxb, const float* __restrict__ vmean)
{
    int tid = blockIdx.x * 256 + threadIdx.x;   // over BL*DM/2
    int pr = tid & 127;
    int b  = tid >> 18;                         // tid / (L*128)
    float v0 = vmean[(b << 8) + pr * 2];
    float v1 = vmean[(b << 8) + pr * 2 + 1];
    ((unsigned int*)ctxb)[tid] = (unsigned int)f2b(v0) | ((unsigned int)f2b(v1) << 16);
}

// h = LN(h + nx)*g + beta ; also writes bf16 copy
__global__ __launch_bounds__(256)
void addln_k(float* __restrict__ h, ushort_t* __restrict__ hb,
             const float* __restrict__ nx,
             const float* __restrict__ g, const float* __restrict__ beta)
{
    int row = blockIdx.x, t = threadIdx.x;
    size_t base = (size_t)row * DM + t;
    float x = h[base] + nx[base];
    float s = x, s2 = x * x;
    #pragma unroll
    for (int off = 32; off > 0; off >>= 1) {
        s  += __shfl_down(s, off);
        s2 += __shfl_down(s2, off);
    }
    __shared__ float ws1[4], ws2[4];
    __shared__ float mean_s, inv_s;
    int wave = t >> 6, lane = t & 63;
    if (lane == 0) { ws1[wave] = s; ws2[wave] = s2; }
    __syncthreads();
    if (t == 0) {
        float ts = ws1[0] + ws1[1] + ws1[2] + ws1[3];
        float t2 = ws2[0] + ws2[1] + ws2[2] + ws2[3];
        float m  = ts * (1.f / (float)DM);
        float var = t2 * (1.f / (float)DM) - m * m;
        mean_s = m;
        inv_s  = 1.0f / sqrtf(var + 1e-5f);
    }
    __syncthreads();
    float res = (x - mean_s) * inv_s * g[t] + beta[t];
    h[base]  = res;
    hb[base] = f2b(res);
}

__global__ __launch_bounds__(512)
void head_k(const float* __restrict__ h, const float* __restrict__ w1,
            const float* __restrict__ b1, const float* __restrict__ w2,
            const float* __restrict__ b2, float* __restrict__ out)
{
    int t = threadIdx.x;
    int b = t >> 6, j = t & 63;
    const float* hr = h + ((size_t)(b * LL + (LL - 1))) * DM;
    float s = 0.f;
    for (int kk = 0; kk < DM; ++kk) s = fmaf(hr[kk], w1[kk * 64 + j], s);
    s += b1[j];
    s = s > 0.f ? s : 0.f;
    float contrib = s * w2[j];
    #pragma unroll
    for (int off = 32; off > 0; off >>= 1) contrib += __shfl_down(contrib, off);
    if (j == 0) out[b] = contrib + b2[0];
}

extern "C" void kernel_launch(void* const* d_in, const int* in_sizes, int n_in,
                              void* d_out, int out_size, void* d_ws, size_t ws_size,
                              hipStream_t stream)
{
    const float* x    = (const float*)d_in[0];
    const int*   idx  = (const int*)  d_in[1];
    const float* w_in = (const float*)d_in[2];
    const float* b_in = (const float*)d_in[3];
    const float* wq   = (const float*)d_in[4];
    const float* bq   = (const float*)d_in[5];
    const float* wk   = (const float*)d_in[6];
    const float* bk   = (const float*)d_in[7];
    const float* wv   = (const float*)d_in[8];
    const float* bv   = (const float*)d_in[9];
    const float* wo   = (const float*)d_in[10];
    const float* bo   = (const float*)d_in[11];
    const float* wf1  = (const float*)d_in[12];
    const float* bf1  = (const float*)d_in[13];
    const float* wf2  = (const float*)d_in[14];
    const float* bf2  = (const float*)d_in[15];
    const float* g1   = (const float*)d_in[16];
    const float* be1  = (const float*)d_in[17];
    const float* g2   = (const float*)d_in[18];
    const float* be2  = (const float*)d_in[19];
    const float* wfc1 = (const float*)d_in[20];
    const float* bfc1 = (const float*)d_in[21];
    const float* wfc2 = (const float*)d_in[22];
    const float* bfc2 = (const float*)d_in[23];
    float* out = (float*)d_out;

    float* ws = (float*)d_ws;
    float*    h     = ws;                          // 4194304
    float*    qkv   = ws + 4194304;                // 12582912
    float*    qb    = qkv;
    float*    kb    = qkv + 4194304;
    float*    vb    = qkv + 8388608;
    float*    newxF = ws + 16777216;               // 4194304 (sub-aliased)
    ushort_t* kb16  = (ushort_t*)newxF;            //   2097152 floats worth
    float*    pm    = newxF + 2097152;             //   524288
    float*    psum  = newxF + 2621440;             //   524288
    float*    mP    = newxF + 3145728;             //   10240
    float*    sP    = newxF + 3155968;             //   10240
    float*    OP    = newxF + 3166208;             //   327680
    ushort_t* xb16  = (ushort_t*)(ws + 20971520);  // 262144 floats
    float*    vme   = ws + 21233664;               // 2048
    int*      top   = (int*)(ws + 21235712);       // 2560
    ushort_t* hb    = (ushort_t*)(ws + 21238272);  // 2097152 floats worth
    ushort_t* wqkvT = (ushort_t*)(ws + 23335424);  // 196608
    ushort_t* woT   = (ushort_t*)(ws + 23532032);  // 65536
    ushort_t* wf1T  = (ushort_t*)(ws + 23597568);  // 262144
    ushort_t* wf2T  = (ushort_t*)(ws + 23859712);  // 262144
    ushort_t* w_inT = (ushort_t*)(ws + 24121856);  // 4096
    float*    bqkv  = ws + 24125952;               // 1536
    ushort_t* ctxb  = (ushort_t*)qkv;              // aliases dead q
    ushort_t* ffbb  = (ushort_t*)(qkv + 2097152);  // aliases dead q/k/v

    dim3 blk(256);

    tcvt_k<<<dim3(2*64),  blk, 0, stream>>>(wq,  wqkvT,           DM, DM,  768*256);
    tcvt_k<<<dim3(2*64),  blk, 0, stream>>>(wk,  wqkvT + 256*256, DM, DM,  768*256);
    tcvt_k<<<dim3(2*64),  blk, 0, stream>>>(wv,  wqkvT + 512*256, DM, DM,  768*256);
    tcvt_k<<<dim3(2*64),  blk, 0, stream>>>(wo,  woT,             DM, DM,  256*256);
    tcvt_k<<<dim3(2*256), blk, 0, stream>>>(wf1, wf1T,            DM, DFF, 1024*256);
    tcvt_k<<<dim3(2*256), blk, 0, stream>>>(wf2, wf2T,            DFF, DM, 256*1024);
    tcvt_k<<<dim3(8),     blk, 0, stream>>>(w_in, w_inT,          32, DM,  256*32);
    bpack_k<<<dim3(6),    blk, 0, stream>>>(bq, bk, bv, bqkv);
    xcvt_k<<<dim3(512),   blk, 0, stream>>>(x, xb16);

    // h = x @ w_in + b_in  (bf16 MFMA, K=32) + bf16 shadow
    gemm_mfma<0,3><<<dim3(BL/128, 2), blk, 0, stream>>>(
        xb16, w_inT, b_in, (void*)h, (void*)hb, BL, DM, 32);

    for (int i = 0; i < 2; ++i) {
        gemm_mfma<0,1><<<dim3(BL/128, 6), blk, 0, stream>>>(
            hb, wqkvT + (size_t)i*768*256, bqkv + i*768, (void*)qkv, (void*)kb16,
            BL, 768, DM);

        metric_k<<<dim3(2048), blk, 0, stream>>>(qb, kb16, idx + (size_t)i*LL*SS, pm, psum);
        topk_k<<<dim3(BB*NH), blk, 0, stream>>>(pm, psum, top);
        vmean_k<<<dim3(BB*NH), blk, 0, stream>>>(vb, vme);
        attnupd_k<<<dim3(BB*NH*4), blk, 0, stream>>>(qb, kb, vb, top, mP, sP, OP);

        fill2_k<<<dim3(BL*DM/512), blk, 0, stream>>>(ctxb, vme);
        combine_k<<<dim3(BB*NH*UU*DH/256), blk, 0, stream>>>(mP, sP, OP, top, ctxb);

        gemm_mfma<0,0><<<dim3(BL/128, 2), blk, 0, stream>>>(
            ctxb, woT + (size_t)i*256*256, bo + i*DM, (void*)newxF, nullptr, BL, DM, DM);
        addln_k<<<dim3(BL), blk, 0, stream>>>(h, hb, newxF, g1 + i*DM, be1 + i*DM);

        gemm_mfma<1,2><<<dim3(BL/128, 8), blk, 0, stream>>>(
            hb, wf1T + (size_t)i*1024*256, bf1 + i*DFF, (void*)ffbb, nullptr, BL, DFF, DM);
        gemm_mfma<0,0><<<dim3(BL/128, 2), blk, 0, stream>>>(
            ffbb, wf2T + (size_t)i*256*1024, bf2 + i*DM, (void*)newxF, nullptr, BL, DM, DFF);
        addln_k<<<dim3(BL), blk, 0, stream>>>(h, hb, newxF, g2 + i*DM, be2 + i*DM);
    }

    head_k<<<dim3(1), dim3(512), 0, stream>>>(h, wfc1, bfc1, wfc2, bfc2, out);
}

// Round 4
// 603.507 us; speedup vs baseline: 2.4873x; 1.0871x over previous
//
#include <hip/hip_runtime.h>
#include <math.h>

#define BB 8
#define LL 2048
#define DM 256
#define NH 8
#define DH 32
#define DFF 1024
#define SS 40
#define UU 40
#define BL (BB*LL)   // 16384
#define NSL 8        // attnupd L-slices per (b,h)

typedef unsigned short ushort_t;
typedef __attribute__((ext_vector_type(8))) short short8;
typedef __attribute__((ext_vector_type(4))) float f32x4;

__device__ inline ushort_t f2b(float f)
{
    unsigned int u = __float_as_uint(f);
    u += 0x7fff + ((u >> 16) & 1);      // round-to-nearest-even
    return (ushort_t)(u >> 16);
}

__device__ inline void gload16(const void* g, const void* l)
{
    __builtin_amdgcn_global_load_lds(
        (const __attribute__((address_space(1))) unsigned int*)g,
        (__attribute__((address_space(3))) unsigned int*)l, 16, 0, 0);
}

// ---------------------------------------------------------------------------
// bf16 MFMA GEMM, m97 structure. 128x128 tile, BK=32, 256 thr.
// OUT_MODE: 0 fp32 RM | 1 QKV scatter (fp32 q,k,v + bf16 k into aux)
//           2 bf16 RM | 3 fp32 RM + bf16 RM into aux
// ---------------------------------------------------------------------------
template<int RELU, int OUT_MODE>
__global__ __launch_bounds__(256)
void gemm_mfma(const ushort_t* __restrict__ A, const ushort_t* __restrict__ Bt,
               const float* __restrict__ bias, void* __restrict__ Cout,
               void* __restrict__ aux, int M, int N, int K)
{
    __shared__ ushort_t Asl[128 * 32];
    __shared__ ushort_t Bsl[128 * 32];

    const int t    = threadIdx.x;
    const int lane = t & 63;
    const int wv   = t >> 6;
    const int row0 = blockIdx.x * 128;
    const int col0 = blockIdx.y * 128;
    const int wr   = (wv >> 1) * 64;
    const int wc   = (wv & 1) * 64;
    const int quad = lane >> 4;
    const int l16  = lane & 15;

    f32x4 acc[4][4];
    #pragma unroll
    for (int i = 0; i < 4; ++i)
        #pragma unroll
        for (int j = 0; j < 4; ++j)
            acc[i][j] = 0.f;

    for (int k0 = 0; k0 < K; k0 += 32) {
        __syncthreads();
        #pragma unroll
        for (int r = 0; r < 2; ++r) {
            int g = r * 256 + t;
            const ushort_t* ga = A  + (size_t)(row0 + (g >> 2)) * K + k0 + (g & 3) * 8;
            const ushort_t* gb = Bt + (size_t)(col0 + (g >> 2)) * K + k0 + (g & 3) * 8;
            int lbase = (r * 256 + wv * 64) * 16;
            gload16(ga, (const char*)Asl + lbase);
            gload16(gb, (const char*)Bsl + lbase);
        }
        __syncthreads();

        short8 af[4], bfr[4];
        #pragma unroll
        for (int mi = 0; mi < 4; ++mi)
            af[mi] = *(const short8*)&Asl[(wr + mi * 16 + l16) * 32 + quad * 8];
        #pragma unroll
        for (int ni = 0; ni < 4; ++ni)
            bfr[ni] = *(const short8*)&Bsl[(wc + ni * 16 + l16) * 32 + quad * 8];
        #pragma unroll
        for (int mi = 0; mi < 4; ++mi)
            #pragma unroll
            for (int ni = 0; ni < 4; ++ni)
                acc[mi][ni] = __builtin_amdgcn_mfma_f32_16x16x32_bf16(
                    af[mi], bfr[ni], acc[mi][ni], 0, 0, 0);
    }

    #pragma unroll
    for (int mi = 0; mi < 4; ++mi) {
        #pragma unroll
        for (int ni = 0; ni < 4; ++ni) {
            int col = col0 + wc + ni * 16 + l16;
            float bb = bias[col];
            #pragma unroll
            for (int r = 0; r < 4; ++r) {
                int row = row0 + wr + mi * 16 + quad * 4 + r;
                float v = acc[mi][ni][r] + bb;
                if (RELU) v = v > 0.f ? v : 0.f;
                if (OUT_MODE == 0) {
                    ((float*)Cout)[(size_t)row * N + col] = v;
                } else if (OUT_MODE == 1) {
                    int tensor = col >> 8;          // 0=q 1=k 2=v
                    int c2 = col & 255;
                    int b  = row >> 11, l = row & (LL - 1);
                    int hh = c2 >> 5,  dh = c2 & 31;
                    size_t bi = (((size_t)(b * NH + hh) * LL + l) << 5) + dh;
                    ((float*)Cout)[(size_t)tensor * (BB*NH*LL*DH) + bi] = v;
                    if (tensor == 1) ((ushort_t*)aux)[bi] = f2b(v);
                } else if (OUT_MODE == 2) {
                    ((ushort_t*)Cout)[(size_t)row * N + col] = f2b(v);
                } else {
                    ((float*)Cout)[(size_t)row * N + col] = v;
                    ((ushort_t*)aux)[(size_t)row * N + col] = f2b(v);
                }
            }
        }
    }
}

// 32x32-tiled transpose + fp32->bf16: dst[m][n][k] = src[m][k][n]
__global__ __launch_bounds__(256)
void tcvt_k(const float* __restrict__ src, ushort_t* __restrict__ dst,
            int K, int N, int matStride)
{
    __shared__ float tile[32][33];
    int tilesN = N >> 5;
    int tpm = (K >> 5) * tilesN;
    int m   = blockIdx.x / tpm;
    int tid = blockIdx.x % tpm;
    int k0 = (tid / tilesN) << 5, n0 = (tid % tilesN) << 5;
    const float* s = src + (size_t)m * K * N;
    ushort_t*    d = dst + (size_t)m * matStride;
    int r = threadIdx.x >> 5, c = threadIdx.x & 31;
    #pragma unroll
    for (int i = 0; i < 4; ++i)
        tile[r + 8 * i][c] = s[(size_t)(k0 + r + 8 * i) * N + n0 + c];
    __syncthreads();
    #pragma unroll
    for (int i = 0; i < 4; ++i)
        d[(size_t)(n0 + r + 8 * i) * K + k0 + c] = f2b(tile[c][r + 8 * i]);
}

// pack bq|bk|bv -> (2,768)
__global__ __launch_bounds__(256)
void bpack_k(const float* __restrict__ bq, const float* __restrict__ bk,
             const float* __restrict__ bv, float* __restrict__ dst)
{
    int t = blockIdx.x * 256 + threadIdx.x;
    int i = t / 768, j = t % 768;
    const float* s = j < 256 ? bq : (j < 512 ? bk : bv);
    dst[t] = s[i * 256 + (j & 255)];
}

// x (fp32) -> bf16, vectorized
__global__ __launch_bounds__(256)
void xcvt_k(const float* __restrict__ x, ushort_t* __restrict__ xb)
{
    int tid = blockIdx.x * 256 + threadIdx.x;
    float4 v = ((const float4*)x)[tid];
    unsigned int lo = f2b(v.x) | ((unsigned int)f2b(v.y) << 16);
    unsigned int hi = f2b(v.z) | ((unsigned int)f2b(v.w) << 16);
    ((uint2*)xb)[tid] = make_uint2(lo, hi);
}

// ---------------------------------------------------------------------------
// metric partials: block = ((bh*4 + sch)*8 + lc); 10 sampled dots per thread
// ---------------------------------------------------------------------------
__global__ __launch_bounds__(256)
void metric_k(const float* __restrict__ qb, const ushort_t* __restrict__ kb16,
              const int* __restrict__ idx, float* __restrict__ pm,
              float* __restrict__ ps)
{
    int blk = blockIdx.x;
    int lc  = blk & 7;
    int sch = (blk >> 3) & 3;
    int bh  = blk >> 5;
    int t   = threadIdx.x;
    int l   = lc * 256 + t;

    float4 q[8];
    const float4* qr = (const float4*)(qb + ((size_t)(bh * LL + l) << 5));
    #pragma unroll
    for (int i = 0; i < 8; ++i) q[i] = qr[i];

    const int* ir = idx + l * SS + sch * 10;
    const uint4* kbase = (const uint4*)(kb16 + ((size_t)bh * LL << 5));

    float mx = -3e38f, sm = 0.f;
    for (int s = 0; s < 10; ++s) {
        int r = ir[s];
        const uint4* kr = kbase + ((size_t)r << 2);
        float d = 0.f;
        #pragma unroll
        for (int w = 0; w < 4; ++w) {
            uint4 kv = kr[w];
            float4 qa = q[2 * w], qb2 = q[2 * w + 1];
            d = fmaf(__uint_as_float(kv.x << 16),        qa.x, d);
            d = fmaf(__uint_as_float(kv.x & 0xffff0000u), qa.y, d);
            d = fmaf(__uint_as_float(kv.y << 16),        qa.z, d);
            d = fmaf(__uint_as_float(kv.y & 0xffff0000u), qa.w, d);
            d = fmaf(__uint_as_float(kv.z << 16),        qb2.x, d);
            d = fmaf(__uint_as_float(kv.z & 0xffff0000u), qb2.y, d);
            d = fmaf(__uint_as_float(kv.w << 16),        qb2.z, d);
            d = fmaf(__uint_as_float(kv.w & 0xffff0000u), qb2.w, d);
        }
        mx = fmaxf(mx, d);
        sm += d;
    }
    pm[(size_t)(sch * 64 + bh) * LL + l] = mx;
    ps[(size_t)(sch * 64 + bh) * LL + l] = sm;
}

// per (b,h): combine metric partials, then top-40 via wave-shuffle argmax
__global__ __launch_bounds__(256)
void topk_k(const float* __restrict__ pm, const float* __restrict__ ps,
            int* __restrict__ top)
{
    __shared__ float vals[LL];
    __shared__ float rv[4];
    __shared__ int   ri[4];
    int bh = blockIdx.x;
    int t  = threadIdx.x;
    for (int i = t; i < LL; i += 256) {
        float m = -3e38f, s = 0.f;
        #pragma unroll
        for (int sch = 0; sch < 4; ++sch) {
            m = fmaxf(m, pm[(size_t)(sch * 64 + bh) * LL + i]);
            s += ps[(size_t)(sch * 64 + bh) * LL + i];
        }
        vals[i] = m - s * (1.0f / (float)LL);
    }
    __syncthreads();
    int lane = t & 63, wvi = t >> 6;
    for (int r = 0; r < UU; ++r) {
        float bv = -3e38f; int bi = 1 << 30;
        for (int i = t; i < LL; i += 256) {
            float v = vals[i];
            if (v > bv) { bv = v; bi = i; }
        }
        #pragma unroll
        for (int off = 32; off > 0; off >>= 1) {
            float ov = __shfl_down(bv, off, 64);
            int   oi = __shfl_down(bi, off, 64);
            if (ov > bv || (ov == bv && oi < bi)) { bv = ov; bi = oi; }
        }
        if (lane == 0) { rv[wvi] = bv; ri[wvi] = bi; }
        __syncthreads();
        if (t == 0) {
            float fv = rv[0]; int fi = ri[0];
            #pragma unroll
            for (int w = 1; w < 4; ++w)
                if (rv[w] > fv || (rv[w] == fv && ri[w] < fi)) { fv = rv[w]; fi = ri[w]; }
            top[bh * UU + r] = fi;
            vals[fi] = -3e38f;
        }
        __syncthreads();
    }
}

__global__ __launch_bounds__(256)
void vmean_k(const float* __restrict__ vb, float* __restrict__ vmean)
{
    __shared__ float red[8][32];
    int bh = blockIdx.x, t = threadIdx.x;
    int d = t & 31, part = t >> 5;
    const float* base = vb + ((size_t)bh * LL << 5);
    float s = 0.f;
    int l0 = part * 256;
    for (int i = 0; i < 256; ++i) s += base[((l0 + i) << 5) + d];
    red[part][d] = s;
    __syncthreads();
    if (t < 32) {
        float tot = 0.f;
        #pragma unroll
        for (int p = 0; p < 8; ++p) tot += red[p][t];
        vmean[bh * 32 + t] = tot * (1.f / (float)LL);
    }
}

// ---------------------------------------------------------------------------
// attnupd v3: block = bh*NSL + slice (512 blocks), 256 l per slice.
// Phase A: per-thread k row in regs, 40 scores via broadcast q reads.
// Phase B: per-j max (float4+shuffle). Phase C: exp pass. Phase D: exp-sums
// per j (shuffle), PV with coalesced V reads.  Partials mP/sP/OP.
// ---------------------------------------------------------------------------
__global__ __launch_bounds__(256)
void attnupd_k(const float* __restrict__ qb, const float* __restrict__ kb,
               const float* __restrict__ vb, const int* __restrict__ top,
               float* __restrict__ mP, float* __restrict__ sP,
               float* __restrict__ OP)
{
    __shared__ float qs[UU * 32];        // 5 KB
    __shared__ float sc[UU * 256];       // 40 KB
    __shared__ float msh[UU];

    int blk = blockIdx.x;
    int sl  = blk & (NSL - 1);
    int bh  = blk >> 3;
    int t   = threadIdx.x;
    int l0  = sl << 8;

    for (int i = t; i < UU * 32; i += 256) {
        int j = i >> 5, dd = i & 31;
        qs[i] = qb[((size_t)(bh * LL + top[bh * UU + j]) << 5) + dd];
    }

    // k row for l = l0 + t
    const float4* kr = (const float4*)(kb + ((size_t)(bh * LL + l0 + t) << 5));
    float4 k4[8];
    #pragma unroll
    for (int i = 0; i < 8; ++i) k4[i] = kr[i];
    __syncthreads();

    const float scale = 0.17677669529663687f;   // 1/sqrt(32)
    #pragma unroll 4
    for (int j = 0; j < UU; ++j) {
        float ds = 0.f;
        #pragma unroll
        for (int i = 0; i < 8; ++i) {
            float4 qv = *(const float4*)&qs[j * 32 + 4 * i];   // broadcast
            ds = fmaf(qv.x, k4[i].x, ds);
            ds = fmaf(qv.y, k4[i].y, ds);
            ds = fmaf(qv.z, k4[i].z, ds);
            ds = fmaf(qv.w, k4[i].w, ds);
        }
        sc[j * 256 + t] = ds * scale;
    }
    __syncthreads();

    int j8 = t >> 5, d = t & 31;
    #pragma unroll
    for (int g = 0; g < 5; ++g) {
        int j = g * 8 + j8;
        float4 a = *(const float4*)&sc[j * 256 + 4 * d];
        float4 b = *(const float4*)&sc[j * 256 + 128 + 4 * d];
        float m = fmaxf(fmaxf(fmaxf(a.x, a.y), fmaxf(a.z, a.w)),
                        fmaxf(fmaxf(b.x, b.y), fmaxf(b.z, b.w)));
        #pragma unroll
        for (int off = 16; off > 0; off >>= 1)
            m = fmaxf(m, __shfl_down(m, off, 64));
        if (d == 0) msh[j] = m;
    }
    __syncthreads();

    // exp pass: thread t handles l = t for every j
    #pragma unroll 8
    for (int i = t; i < UU * 256; i += 256) {
        int j = i >> 8;
        sc[i] = __expf(sc[i] - msh[j]);
    }
    __syncthreads();

    int pq = bh * NSL + sl;

    // exp-sums per j (only once, via shuffle)
    #pragma unroll
    for (int g = 0; g < 5; ++g) {
        int j = g * 8 + j8;
        float4 a = *(const float4*)&sc[j * 256 + 4 * d];
        float4 b = *(const float4*)&sc[j * 256 + 128 + 4 * d];
        float s = a.x + a.y + a.z + a.w + b.x + b.y + b.z + b.w;
        #pragma unroll
        for (int off = 16; off > 0; off >>= 1)
            s += __shfl_down(s, off, 64);
        if (d == 0) { sP[pq * UU + j] = s; mP[pq * UU + j] = msh[j]; }
    }

    // PV: acc[g] for j = g*8 + j8, dim d; V reads coalesced (one line per l)
    const float* vbase = vb + ((size_t)(bh * LL + l0) << 5) + d;
    float acc[5] = {0.f, 0.f, 0.f, 0.f, 0.f};
    #pragma unroll 4
    for (int i = 0; i < 64; ++i) {
        float v0 = vbase[(4 * i + 0) << 5];
        float v1 = vbase[(4 * i + 1) << 5];
        float v2 = vbase[(4 * i + 2) << 5];
        float v3 = vbase[(4 * i + 3) << 5];
        #pragma unroll
        for (int g = 0; g < 5; ++g) {
            float4 e4 = *(const float4*)&sc[(g * 8 + j8) * 256 + 4 * i]; // broadcast
            acc[g] = fmaf(e4.x, v0, acc[g]);
            acc[g] = fmaf(e4.y, v1, acc[g]);
            acc[g] = fmaf(e4.z, v2, acc[g]);
            acc[g] = fmaf(e4.w, v3, acc[g]);
        }
    }
    #pragma unroll
    for (int g = 0; g < 5; ++g) {
        int j = g * 8 + j8;
        OP[((size_t)pq * UU + j) * 32 + d] = acc[g];
    }
}

// merge NSL slice-partials, normalize, scatter bf16 into ctx
__global__ __launch_bounds__(256)
void combine_k(const float* __restrict__ mP, const float* __restrict__ sP,
               const float* __restrict__ OP, const int* __restrict__ top,
               ushort_t* __restrict__ ctxb)
{
    int tid = blockIdx.x * 256 + threadIdx.x;   // < 64*40*32
    int d  = tid & 31;
    int j  = (tid >> 5) % UU;
    int bh = tid / (UU * 32);
    float M = -3e38f;
    #pragma unroll
    for (int q = 0; q < NSL; ++q) M = fmaxf(M, mP[(bh * NSL + q) * UU + j]);
    float S = 0.f, O = 0.f;
    #pragma unroll
    for (int q = 0; q < NSL; ++q) {
        float w = __expf(mP[(bh * NSL + q) * UU + j] - M);
        S = fmaf(sP[(bh * NSL + q) * UU + j], w, S);
        O = fmaf(OP[((size_t)(bh * NSL + q) * UU + j) * 32 + d], w, O);
    }
    float u = O / S;
    int qi = top[bh * UU + j];
    int b = bh >> 3, hh = bh & 7;
    ctxb[(((size_t)(b * LL + qi)) << 8) + (hh << 5) + d] = f2b(u);
}

// ctx bf16 fill with vmean broadcast (2 elems/thread packed)
__global__ __launch_bounds__(256)
void fill2_k(ushort_t* __restrict__ ctxb, const float* __restrict__ vmean)
{
    int tid = blockIdx.x * 256 + threadIdx.x;
    int pr = tid & 127;
    int b  = tid >> 18;
    float v0 = vmean[(b << 8) + pr * 2];
    float v1 = vmean[(b << 8) + pr * 2 + 1];
    ((unsigned int*)ctxb)[tid] = (unsigned int)f2b(v0) | ((unsigned int)f2b(v1) << 16);
}

// h = LN(h + nx)*g + beta ; also writes bf16 copy
__global__ __launch_bounds__(256)
void addln_k(float* __restrict__ h, ushort_t* __restrict__ hb,
             const float* __restrict__ nx,
             const float* __restrict__ g, const float* __restrict__ beta)
{
    int row = blockIdx.x, t = threadIdx.x;
    size_t base = (size_t)row * DM + t;
    float x = h[base] + nx[base];
    float s = x, s2 = x * x;
    #pragma unroll
    for (int off = 32; off > 0; off >>= 1) {
        s  += __shfl_down(s, off);
        s2 += __shfl_down(s2, off);
    }
    __shared__ float ws1[4], ws2[4];
    __shared__ float mean_s, inv_s;
    int wave = t >> 6, lane = t & 63;
    if (lane == 0) { ws1[wave] = s; ws2[wave] = s2; }
    __syncthreads();
    if (t == 0) {
        float ts = ws1[0] + ws1[1] + ws1[2] + ws1[3];
        float t2 = ws2[0] + ws2[1] + ws2[2] + ws2[3];
        float m  = ts * (1.f / (float)DM);
        float var = t2 * (1.f / (float)DM) - m * m;
        mean_s = m;
        inv_s  = 1.0f / sqrtf(var + 1e-5f);
    }
    __syncthreads();
    float res = (x - mean_s) * inv_s * g[t] + beta[t];
    h[base]  = res;
    hb[base] = f2b(res);
}

__global__ __launch_bounds__(512)
void head_k(const float* __restrict__ h, const float* __restrict__ w1,
            const float* __restrict__ b1, const float* __restrict__ w2,
            const float* __restrict__ b2, float* __restrict__ out)
{
    int t = threadIdx.x;
    int b = t >> 6, j = t & 63;
    const float* hr = h + ((size_t)(b * LL + (LL - 1))) * DM;
    float s = 0.f;
    for (int kk = 0; kk < DM; ++kk) s = fmaf(hr[kk], w1[kk * 64 + j], s);
    s += b1[j];
    s = s > 0.f ? s : 0.f;
    float contrib = s * w2[j];
    #pragma unroll
    for (int off = 32; off > 0; off >>= 1) contrib += __shfl_down(contrib, off);
    if (j == 0) out[b] = contrib + b2[0];
}

extern "C" void kernel_launch(void* const* d_in, const int* in_sizes, int n_in,
                              void* d_out, int out_size, void* d_ws, size_t ws_size,
                              hipStream_t stream)
{
    const float* x    = (const float*)d_in[0];
    const int*   idx  = (const int*)  d_in[1];
    const float* w_in = (const float*)d_in[2];
    const float* b_in = (const float*)d_in[3];
    const float* wq   = (const float*)d_in[4];
    const float* bq   = (const float*)d_in[5];
    const float* wk   = (const float*)d_in[6];
    const float* bk   = (const float*)d_in[7];
    const float* wv   = (const float*)d_in[8];
    const float* bv   = (const float*)d_in[9];
    const float* wo   = (const float*)d_in[10];
    const float* bo   = (const float*)d_in[11];
    const float* wf1  = (const float*)d_in[12];
    const float* bf1  = (const float*)d_in[13];
    const float* wf2  = (const float*)d_in[14];
    const float* bf2  = (const float*)d_in[15];
    const float* g1   = (const float*)d_in[16];
    const float* be1  = (const float*)d_in[17];
    const float* g2   = (const float*)d_in[18];
    const float* be2  = (const float*)d_in[19];
    const float* wfc1 = (const float*)d_in[20];
    const float* bfc1 = (const float*)d_in[21];
    const float* wfc2 = (const float*)d_in[22];
    const float* bfc2 = (const float*)d_in[23];
    float* out = (float*)d_out;

    float* ws = (float*)d_ws;
    float*    h     = ws;                          // 4194304
    float*    qkv   = ws + 4194304;                // 12582912
    float*    qb    = qkv;
    float*    kb    = qkv + 4194304;
    float*    vb    = qkv + 8388608;
    float*    newxF = ws + 16777216;               // 4194304 (sub-aliased)
    ushort_t* kb16  = (ushort_t*)newxF;            //   [0, 2097152) floats
    float*    pm    = newxF + 2097152;             //   [2097152, 2621440)
    float*    psum  = newxF + 2621440;             //   [2621440, 3145728)
    float*    OP    = newxF + 2097152;             //   aliases pm/psum (dead by attnupd)
    float*    mP    = newxF + 2752512;             //   20480
    float*    sP    = newxF + 2772992;             //   20480
    ushort_t* xb16  = (ushort_t*)(ws + 20971520);  // 262144 floats
    float*    vme   = ws + 21233664;               // 2048
    int*      top   = (int*)(ws + 21235712);       // 2560
    ushort_t* hb    = (ushort_t*)(ws + 21238272);  // 2097152 floats worth
    ushort_t* wqkvT = (ushort_t*)(ws + 23335424);  // 196608
    ushort_t* woT   = (ushort_t*)(ws + 23532032);  // 65536
    ushort_t* wf1T  = (ushort_t*)(ws + 23597568);  // 262144
    ushort_t* wf2T  = (ushort_t*)(ws + 23859712);  // 262144
    ushort_t* w_inT = (ushort_t*)(ws + 24121856);  // 4096
    float*    bqkv  = ws + 24125952;               // 1536
    ushort_t* ctxb  = (ushort_t*)qkv;              // aliases dead q
    ushort_t* ffbb  = (ushort_t*)(qkv + 2097152);  // aliases dead q/k/v

    dim3 blk(256);

    tcvt_k<<<dim3(2*64),  blk, 0, stream>>>(wq,  wqkvT,           DM, DM,  768*256);
    tcvt_k<<<dim3(2*64),  blk, 0, stream>>>(wk,  wqkvT + 256*256, DM, DM,  768*256);
    tcvt_k<<<dim3(2*64),  blk, 0, stream>>>(wv,  wqkvT + 512*256, DM, DM,  768*256);
    tcvt_k<<<dim3(2*64),  blk, 0, stream>>>(wo,  woT,             DM, DM,  256*256);
    tcvt_k<<<dim3(2*256), blk, 0, stream>>>(wf1, wf1T,            DM, DFF, 1024*256);
    tcvt_k<<<dim3(2*256), blk, 0, stream>>>(wf2, wf2T,            DFF, DM, 256*1024);
    tcvt_k<<<dim3(8),     blk, 0, stream>>>(w_in, w_inT,          32, DM,  256*32);
    bpack_k<<<dim3(6),    blk, 0, stream>>>(bq, bk, bv, bqkv);
    xcvt_k<<<dim3(512),   blk, 0, stream>>>(x, xb16);

    gemm_mfma<0,3><<<dim3(BL/128, 2), blk, 0, stream>>>(
        xb16, w_inT, b_in, (void*)h, (void*)hb, BL, DM, 32);

    for (int i = 0; i < 2; ++i) {
        gemm_mfma<0,1><<<dim3(BL/128, 6), blk, 0, stream>>>(
            hb, wqkvT + (size_t)i*768*256, bqkv + i*768, (void*)qkv, (void*)kb16,
            BL, 768, DM);

        metric_k<<<dim3(2048), blk, 0, stream>>>(qb, kb16, idx + (size_t)i*LL*SS, pm, psum);
        topk_k<<<dim3(BB*NH), blk, 0, stream>>>(pm, psum, top);
        vmean_k<<<dim3(BB*NH), blk, 0, stream>>>(vb, vme);
        attnupd_k<<<dim3(BB*NH*NSL), blk, 0, stream>>>(qb, kb, vb, top, mP, sP, OP);

        fill2_k<<<dim3(BL*DM/512), blk, 0, stream>>>(ctxb, vme);
        combine_k<<<dim3(BB*NH*UU*DH/256), blk, 0, stream>>>(mP, sP, OP, top, ctxb);

        gemm_mfma<0,0><<<dim3(BL/128, 2), blk, 0, stream>>>(
            ctxb, woT + (size_t)i*256*256, bo + i*DM, (void*)newxF, nullptr, BL, DM, DM);
        addln_k<<<dim3(BL), blk, 0, stream>>>(h, hb, newxF, g1 + i*DM, be1 + i*DM);

        gemm_mfma<1,2><<<dim3(BL/128, 8), blk, 0, stream>>>(
            hb, wf1T + (size_t)i*1024*256, bf1 + i*DFF, (void*)ffbb, nullptr, BL, DFF, DM);
        gemm_mfma<0,0><<<dim3(BL/128, 2), blk, 0, stream>>>(
            ffbb, wf2T + (size_t)i*256*1024, bf2 + i*DM, (void*)newxF, nullptr, BL, DM, DFF);
        addln_k<<<dim3(BL), blk, 0, stream>>>(h, hb, newxF, g2 + i*DM, be2 + i*DM);
    }

    head_k<<<dim3(1), dim3(512), 0, stream>>>(h, wfc1, bfc1, wfc2, bfc2, out);
}

// Round 5
// 567.005 us; speedup vs baseline: 2.6474x; 1.0644x over previous
//
#include <hip/hip_runtime.h>
#include <math.h>

#define BB 8
#define LL 2048
#define DM 256
#define NH 8
#define DH 32
#define DFF 1024
#define SS 40
#define UU 40
#define BL (BB*LL)   // 16384
#define NSL 8        // attnupd L-slices per (b,h)

typedef unsigned short ushort_t;
typedef __attribute__((ext_vector_type(8))) short short8;
typedef __attribute__((ext_vector_type(4))) float f32x4;

__device__ inline ushort_t f2b(float f)
{
    unsigned int u = __float_as_uint(f);
    u += 0x7fff + ((u >> 16) & 1);      // round-to-nearest-even
    return (ushort_t)(u >> 16);
}

__device__ inline void gload16(const void* g, const void* l)
{
    __builtin_amdgcn_global_load_lds(
        (const __attribute__((address_space(1))) unsigned int*)g,
        (__attribute__((address_space(3))) unsigned int*)l, 16, 0, 0);
}

// ---------------------------------------------------------------------------
// bf16 MFMA GEMM, m97 structure. 128x128 tile, BK=32, 256 thr.
// OUT_MODE: 0 fp32 RM | 1 QKV scatter (fp32 q,k,v + bf16 k into aux)
//           2 bf16 RM | 3 fp32 RM + bf16 RM into aux
// ---------------------------------------------------------------------------
template<int RELU, int OUT_MODE>
__global__ __launch_bounds__(256)
void gemm_mfma(const ushort_t* __restrict__ A, const ushort_t* __restrict__ Bt,
               const float* __restrict__ bias, void* __restrict__ Cout,
               void* __restrict__ aux, int M, int N, int K)
{
    __shared__ ushort_t Asl[128 * 32];
    __shared__ ushort_t Bsl[128 * 32];

    const int t    = threadIdx.x;
    const int lane = t & 63;
    const int wv   = t >> 6;
    const int row0 = blockIdx.x * 128;
    const int col0 = blockIdx.y * 128;
    const int wr   = (wv >> 1) * 64;
    const int wc   = (wv & 1) * 64;
    const int quad = lane >> 4;
    const int l16  = lane & 15;

    f32x4 acc[4][4];
    #pragma unroll
    for (int i = 0; i < 4; ++i)
        #pragma unroll
        for (int j = 0; j < 4; ++j)
            acc[i][j] = 0.f;

    for (int k0 = 0; k0 < K; k0 += 32) {
        __syncthreads();
        #pragma unroll
        for (int r = 0; r < 2; ++r) {
            int g = r * 256 + t;
            const ushort_t* ga = A  + (size_t)(row0 + (g >> 2)) * K + k0 + (g & 3) * 8;
            const ushort_t* gb = Bt + (size_t)(col0 + (g >> 2)) * K + k0 + (g & 3) * 8;
            int lbase = (r * 256 + wv * 64) * 16;
            gload16(ga, (const char*)Asl + lbase);
            gload16(gb, (const char*)Bsl + lbase);
        }
        __syncthreads();

        short8 af[4], bfr[4];
        #pragma unroll
        for (int mi = 0; mi < 4; ++mi)
            af[mi] = *(const short8*)&Asl[(wr + mi * 16 + l16) * 32 + quad * 8];
        #pragma unroll
        for (int ni = 0; ni < 4; ++ni)
            bfr[ni] = *(const short8*)&Bsl[(wc + ni * 16 + l16) * 32 + quad * 8];
        #pragma unroll
        for (int mi = 0; mi < 4; ++mi)
            #pragma unroll
            for (int ni = 0; ni < 4; ++ni)
                acc[mi][ni] = __builtin_amdgcn_mfma_f32_16x16x32_bf16(
                    af[mi], bfr[ni], acc[mi][ni], 0, 0, 0);
    }

    #pragma unroll
    for (int mi = 0; mi < 4; ++mi) {
        #pragma unroll
        for (int ni = 0; ni < 4; ++ni) {
            int col = col0 + wc + ni * 16 + l16;
            float bb = bias[col];
            #pragma unroll
            for (int r = 0; r < 4; ++r) {
                int row = row0 + wr + mi * 16 + quad * 4 + r;
                float v = acc[mi][ni][r] + bb;
                if (RELU) v = v > 0.f ? v : 0.f;
                if (OUT_MODE == 0) {
                    ((float*)Cout)[(size_t)row * N + col] = v;
                } else if (OUT_MODE == 1) {
                    int tensor = col >> 8;          // 0=q 1=k 2=v
                    int c2 = col & 255;
                    int b  = row >> 11, l = row & (LL - 1);
                    int hh = c2 >> 5,  dh = c2 & 31;
                    size_t bi = (((size_t)(b * NH + hh) * LL + l) << 5) + dh;
                    ((float*)Cout)[(size_t)tensor * (BB*NH*LL*DH) + bi] = v;
                    if (tensor == 1) ((ushort_t*)aux)[bi] = f2b(v);
                } else if (OUT_MODE == 2) {
                    ((ushort_t*)Cout)[(size_t)row * N + col] = f2b(v);
                } else {
                    ((float*)Cout)[(size_t)row * N + col] = v;
                    ((ushort_t*)aux)[(size_t)row * N + col] = f2b(v);
                }
            }
        }
    }
}

// ---------------------------------------------------------------------------
// 64x128-tile MFMA GEMM (fp32 out) — for N=256 GEMMs: 2x the blocks/CU.
// 4 waves, wave wv covers cols wv*32..wv*32+31 of the 128-col tile.
// ---------------------------------------------------------------------------
__global__ __launch_bounds__(256)
void gemm64_k(const ushort_t* __restrict__ A, const ushort_t* __restrict__ Bt,
              const float* __restrict__ bias, float* __restrict__ Cout,
              int M, int N, int K)
{
    __shared__ ushort_t Asl[64 * 32];
    __shared__ ushort_t Bsl[128 * 32];

    const int t    = threadIdx.x;
    const int lane = t & 63;
    const int wv   = t >> 6;
    const int row0 = blockIdx.x * 64;
    const int col0 = blockIdx.y * 128;
    const int wc   = wv * 32;
    const int quad = lane >> 4;
    const int l16  = lane & 15;

    f32x4 acc[4][2];
    #pragma unroll
    for (int i = 0; i < 4; ++i) { acc[i][0] = 0.f; acc[i][1] = 0.f; }

    for (int k0 = 0; k0 < K; k0 += 32) {
        __syncthreads();
        {
            const ushort_t* ga = A + (size_t)(row0 + (t >> 2)) * K + k0 + (t & 3) * 8;
            gload16(ga, (const char*)Asl + wv * 64 * 16);
        }
        #pragma unroll
        for (int r = 0; r < 2; ++r) {
            int g = r * 256 + t;
            const ushort_t* gb = Bt + (size_t)(col0 + (g >> 2)) * K + k0 + (g & 3) * 8;
            gload16(gb, (const char*)Bsl + (r * 256 + wv * 64) * 16);
        }
        __syncthreads();

        short8 af[4], bfr[2];
        #pragma unroll
        for (int mi = 0; mi < 4; ++mi)
            af[mi] = *(const short8*)&Asl[(mi * 16 + l16) * 32 + quad * 8];
        #pragma unroll
        for (int ni = 0; ni < 2; ++ni)
            bfr[ni] = *(const short8*)&Bsl[(wc + ni * 16 + l16) * 32 + quad * 8];
        #pragma unroll
        for (int mi = 0; mi < 4; ++mi)
            #pragma unroll
            for (int ni = 0; ni < 2; ++ni)
                acc[mi][ni] = __builtin_amdgcn_mfma_f32_16x16x32_bf16(
                    af[mi], bfr[ni], acc[mi][ni], 0, 0, 0);
    }

    #pragma unroll
    for (int mi = 0; mi < 4; ++mi) {
        #pragma unroll
        for (int ni = 0; ni < 2; ++ni) {
            int col = col0 + wc + ni * 16 + l16;
            float bb = bias[col];
            #pragma unroll
            for (int r = 0; r < 4; ++r) {
                int row = row0 + mi * 16 + quad * 4 + r;
                Cout[(size_t)row * N + col] = acc[mi][ni][r] + bb;
            }
        }
    }
}

// ---------------------------------------------------------------------------
// fused preproc: all weight transposes+cvt, bias pack, x cvt in ONE dispatch.
// grid 2062 x 256.
// ---------------------------------------------------------------------------
__device__ inline void tcvt_dev(float (*tile)[33], const float* __restrict__ src,
                                ushort_t* __restrict__ dst, int K, int N,
                                int matStride, int bi)
{
    int tilesN = N >> 5;
    int tpm = (K >> 5) * tilesN;
    int m   = bi / tpm;
    int tid = bi % tpm;
    int k0 = (tid / tilesN) << 5, n0 = (tid % tilesN) << 5;
    const float* s = src + (size_t)m * K * N;
    ushort_t*    d = dst + (size_t)m * matStride;
    int r = threadIdx.x >> 5, c = threadIdx.x & 31;
    #pragma unroll
    for (int i = 0; i < 4; ++i)
        tile[r + 8 * i][c] = s[(size_t)(k0 + r + 8 * i) * N + n0 + c];
    __syncthreads();
    #pragma unroll
    for (int i = 0; i < 4; ++i)
        d[(size_t)(n0 + r + 8 * i) * K + k0 + c] = f2b(tile[c][r + 8 * i]);
}

__global__ __launch_bounds__(256)
void preproc_k(const float* __restrict__ wq, const float* __restrict__ wk,
               const float* __restrict__ wv, const float* __restrict__ wo,
               const float* __restrict__ wf1, const float* __restrict__ wf2,
               const float* __restrict__ w_in,
               const float* __restrict__ bq, const float* __restrict__ bk,
               const float* __restrict__ bv, const float* __restrict__ x,
               ushort_t* __restrict__ wqkvT, ushort_t* __restrict__ woT,
               ushort_t* __restrict__ wf1T, ushort_t* __restrict__ wf2T,
               ushort_t* __restrict__ w_inT, float* __restrict__ bqkv,
               ushort_t* __restrict__ xb16)
{
    __shared__ float tile[32][33];
    int b = blockIdx.x;
    if (b < 512) {                       // wq|wk|wv|wo, 128 blocks each
        int which = b >> 7, lb = b & 127;
        const float* src = which == 0 ? wq : which == 1 ? wk : which == 2 ? wv : wo;
        ushort_t* dst = which == 0 ? wqkvT : which == 1 ? wqkvT + 65536
                       : which == 2 ? wqkvT + 131072 : woT;
        int stride = which == 3 ? 65536 : 768 * 256;
        tcvt_dev(tile, src, dst, DM, DM, stride, lb);
    } else if (b < 1024) {
        tcvt_dev(tile, wf1, wf1T, DM, DFF, 1024 * 256, b - 512);
    } else if (b < 1536) {
        tcvt_dev(tile, wf2, wf2T, DFF, DM, 256 * 1024, b - 1024);
    } else if (b < 1544) {
        tcvt_dev(tile, w_in, w_inT, 32, DM, 256 * 32, b - 1536);
    } else if (b < 1550) {
        int t = (b - 1544) * 256 + threadIdx.x;      // 0..1535
        int i = t / 768, j = t % 768;
        const float* s = j < 256 ? bq : (j < 512 ? bk : bv);
        bqkv[t] = s[i * 256 + (j & 255)];
    } else {
        int tid = (b - 1550) * 256 + threadIdx.x;    // over 131072 float4s
        float4 v = ((const float4*)x)[tid];
        unsigned int lo = f2b(v.x) | ((unsigned int)f2b(v.y) << 16);
        unsigned int hi = f2b(v.z) | ((unsigned int)f2b(v.w) << 16);
        ((uint2*)xb16)[tid] = make_uint2(lo, hi);
    }
}

// ---------------------------------------------------------------------------
// metric partials: block = ((bh*4 + sch)*8 + lc); 10 sampled dots per thread
// ---------------------------------------------------------------------------
__global__ __launch_bounds__(256)
void metric_k(const float* __restrict__ qb, const ushort_t* __restrict__ kb16,
              const int* __restrict__ idx, float* __restrict__ pm,
              float* __restrict__ ps)
{
    int blk = blockIdx.x;
    int lc  = blk & 7;
    int sch = (blk >> 3) & 3;
    int bh  = blk >> 5;
    int t   = threadIdx.x;
    int l   = lc * 256 + t;

    float4 q[8];
    const float4* qr = (const float4*)(qb + ((size_t)(bh * LL + l) << 5));
    #pragma unroll
    for (int i = 0; i < 8; ++i) q[i] = qr[i];

    const int* ir = idx + l * SS + sch * 10;
    const uint4* kbase = (const uint4*)(kb16 + ((size_t)bh * LL << 5));

    float mx = -3e38f, sm = 0.f;
    for (int s = 0; s < 10; ++s) {
        int r = ir[s];
        const uint4* kr = kbase + ((size_t)r << 2);
        float d = 0.f;
        #pragma unroll
        for (int w = 0; w < 4; ++w) {
            uint4 kv = kr[w];
            float4 qa = q[2 * w], qb2 = q[2 * w + 1];
            d = fmaf(__uint_as_float(kv.x << 16),        qa.x, d);
            d = fmaf(__uint_as_float(kv.x & 0xffff0000u), qa.y, d);
            d = fmaf(__uint_as_float(kv.y << 16),        qa.z, d);
            d = fmaf(__uint_as_float(kv.y & 0xffff0000u), qa.w, d);
            d = fmaf(__uint_as_float(kv.z << 16),        qb2.x, d);
            d = fmaf(__uint_as_float(kv.z & 0xffff0000u), qb2.y, d);
            d = fmaf(__uint_as_float(kv.w << 16),        qb2.z, d);
            d = fmaf(__uint_as_float(kv.w & 0xffff0000u), qb2.w, d);
        }
        mx = fmaxf(mx, d);
        sm += d;
    }
    pm[(size_t)(sch * 64 + bh) * LL + l] = mx;
    ps[(size_t)(sch * 64 + bh) * LL + l] = sm;
}

// ---------------------------------------------------------------------------
// topk stage 1: wave-synchronous per-slice top-40 (no barriers).
// grid 128 x 256: wave handles slice (blk*4 + wave) of 256 elements.
// ---------------------------------------------------------------------------
__global__ __launch_bounds__(256)
void topk1_k(const float* __restrict__ pm, const float* __restrict__ ps,
             float* __restrict__ cand_v, int* __restrict__ cand_i)
{
    int lane = threadIdx.x & 63;
    int slg  = blockIdx.x * 4 + (threadIdx.x >> 6);   // 0..511
    int bh   = slg >> 3;
    int l0   = (slg & 7) << 8;

    float v[4];
    #pragma unroll
    for (int i = 0; i < 4; ++i) {
        int l = l0 + i * 64 + lane;
        float m = -3e38f, s = 0.f;
        #pragma unroll
        for (int sch = 0; sch < 4; ++sch) {
            m = fmaxf(m, pm[(size_t)(sch * 64 + bh) * LL + l]);
            s += ps[(size_t)(sch * 64 + bh) * LL + l];
        }
        v[i] = m - s * (1.0f / (float)LL);
    }

    for (int r = 0; r < UU; ++r) {
        float bv = -3e38f; int bi = 1 << 30;
        #pragma unroll
        for (int i = 0; i < 4; ++i) {
            int idx = l0 + i * 64 + lane;
            if (v[i] > bv || (v[i] == bv && idx < bi)) { bv = v[i]; bi = idx; }
        }
        #pragma unroll
        for (int off = 32; off > 0; off >>= 1) {
            float ov = __shfl_down(bv, off, 64);
            int   oi = __shfl_down(bi, off, 64);
            if (ov > bv || (ov == bv && oi < bi)) { bv = ov; bi = oi; }
        }
        bv = __shfl(bv, 0, 64);
        bi = __shfl(bi, 0, 64);
        if (lane == 0) {
            cand_v[slg * UU + r] = bv;
            cand_i[slg * UU + r] = bi;
        }
        int rel = bi - l0;
        if ((rel & 63) == lane) v[rel >> 6] = -3e38f;
    }
}

// topk stage 2: rank-select top-40 from 320 candidates per bh.
__global__ __launch_bounds__(256)
void topk2_k(const float* __restrict__ cand_v, const int* __restrict__ cand_i,
             int* __restrict__ top)
{
    __shared__ float cv[320];
    __shared__ int   ci[320];
    int bh = blockIdx.x, t = threadIdx.x;
    for (int i = t; i < 320; i += 256) {
        cv[i] = cand_v[bh * 320 + i];
        ci[i] = cand_i[bh * 320 + i];
    }
    __syncthreads();
    for (int c = t; c < 320; c += 256) {
        float mv = cv[c]; int mi = ci[c];
        int rank = 0;
        for (int j = 0; j < 320; ++j)
            rank += (cv[j] > mv) || (cv[j] == mv && ci[j] < mi);
        if (rank < UU) top[bh * UU + rank] = mi;
    }
}

// vmean partials: grid 512 (bh x 8 slices), 32 rows per 32-thread part
__global__ __launch_bounds__(256)
void vmeanp_k(const float* __restrict__ vb, float* __restrict__ vmeP)
{
    __shared__ float red[8][32];
    int blk = blockIdx.x;
    int bh = blk >> 3, sl = blk & 7;
    int t = threadIdx.x;
    int d = t & 31, part = t >> 5;
    const float* base = vb + ((size_t)(bh * LL + sl * 256 + part * 32) << 5);
    float s = 0.f;
    #pragma unroll 8
    for (int i = 0; i < 32; ++i) s += base[(i << 5) + d];
    red[part][d] = s;
    __syncthreads();
    if (t < 32) {
        float tot = 0.f;
        #pragma unroll
        for (int p = 0; p < 8; ++p) tot += red[p][t];
        vmeP[blk * 32 + t] = tot;
    }
}

// final vmean: 8 blocks x 256 threads over 64*32 outputs
__global__ __launch_bounds__(256)
void vfin_k(const float* __restrict__ vmeP, float* __restrict__ vme)
{
    int tid = blockIdx.x * 256 + threadIdx.x;   // < 2048
    int bh = tid >> 5, d = tid & 31;
    float s = 0.f;
    #pragma unroll
    for (int sl = 0; sl < 8; ++sl) s += vmeP[(bh * 8 + sl) * 32 + d];
    vme[tid] = s * (1.f / (float)LL);
}

// ---------------------------------------------------------------------------
// attnupd: block = bh*NSL + slice (512 blocks), 256 l per slice.
// ---------------------------------------------------------------------------
__global__ __launch_bounds__(256)
void attnupd_k(const float* __restrict__ qb, const float* __restrict__ kb,
               const float* __restrict__ vb, const int* __restrict__ top,
               float* __restrict__ mP, float* __restrict__ sP,
               float* __restrict__ OP)
{
    __shared__ float qs[UU * 32];        // 5 KB
    __shared__ float sc[UU * 256];       // 40 KB
    __shared__ float msh[UU];

    int blk = blockIdx.x;
    int sl  = blk & (NSL - 1);
    int bh  = blk >> 3;
    int t   = threadIdx.x;
    int l0  = sl << 8;

    for (int i = t; i < UU * 32; i += 256) {
        int j = i >> 5, dd = i & 31;
        qs[i] = qb[((size_t)(bh * LL + top[bh * UU + j]) << 5) + dd];
    }

    const float4* kr = (const float4*)(kb + ((size_t)(bh * LL + l0 + t) << 5));
    float4 k4[8];
    #pragma unroll
    for (int i = 0; i < 8; ++i) k4[i] = kr[i];
    __syncthreads();

    const float scale = 0.17677669529663687f;   // 1/sqrt(32)
    #pragma unroll 4
    for (int j = 0; j < UU; ++j) {
        float ds = 0.f;
        #pragma unroll
        for (int i = 0; i < 8; ++i) {
            float4 qv = *(const float4*)&qs[j * 32 + 4 * i];   // broadcast
            ds = fmaf(qv.x, k4[i].x, ds);
            ds = fmaf(qv.y, k4[i].y, ds);
            ds = fmaf(qv.z, k4[i].z, ds);
            ds = fmaf(qv.w, k4[i].w, ds);
        }
        sc[j * 256 + t] = ds * scale;
    }
    __syncthreads();

    int j8 = t >> 5, d = t & 31;
    #pragma unroll
    for (int g = 0; g < 5; ++g) {
        int j = g * 8 + j8;
        float4 a = *(const float4*)&sc[j * 256 + 4 * d];
        float4 b = *(const float4*)&sc[j * 256 + 128 + 4 * d];
        float m = fmaxf(fmaxf(fmaxf(a.x, a.y), fmaxf(a.z, a.w)),
                        fmaxf(fmaxf(b.x, b.y), fmaxf(b.z, b.w)));
        #pragma unroll
        for (int off = 16; off > 0; off >>= 1)
            m = fmaxf(m, __shfl_down(m, off, 64));
        if (d == 0) msh[j] = m;
    }
    __syncthreads();

    #pragma unroll 8
    for (int i = t; i < UU * 256; i += 256) {
        int j = i >> 8;
        sc[i] = __expf(sc[i] - msh[j]);
    }
    __syncthreads();

    int pq = bh * NSL + sl;

    #pragma unroll
    for (int g = 0; g < 5; ++g) {
        int j = g * 8 + j8;
        float4 a = *(const float4*)&sc[j * 256 + 4 * d];
        float4 b = *(const float4*)&sc[j * 256 + 128 + 4 * d];
        float s = a.x + a.y + a.z + a.w + b.x + b.y + b.z + b.w;
        #pragma unroll
        for (int off = 16; off > 0; off >>= 1)
            s += __shfl_down(s, off, 64);
        if (d == 0) { sP[pq * UU + j] = s; mP[pq * UU + j] = msh[j]; }
    }

    const float* vbase = vb + ((size_t)(bh * LL + l0) << 5) + d;
    float acc[5] = {0.f, 0.f, 0.f, 0.f, 0.f};
    #pragma unroll 4
    for (int i = 0; i < 64; ++i) {
        float v0 = vbase[(4 * i + 0) << 5];
        float v1 = vbase[(4 * i + 1) << 5];
        float v2 = vbase[(4 * i + 2) << 5];
        float v3 = vbase[(4 * i + 3) << 5];
        #pragma unroll
        for (int g = 0; g < 5; ++g) {
            float4 e4 = *(const float4*)&sc[(g * 8 + j8) * 256 + 4 * i];
            acc[g] = fmaf(e4.x, v0, acc[g]);
            acc[g] = fmaf(e4.y, v1, acc[g]);
            acc[g] = fmaf(e4.z, v2, acc[g]);
            acc[g] = fmaf(e4.w, v3, acc[g]);
        }
    }
    #pragma unroll
    for (int g = 0; g < 5; ++g)
        OP[((size_t)pq * UU + g * 8 + j8) * 32 + d] = acc[g];
}

// merge NSL slice-partials, normalize, scatter bf16 into ctx
__global__ __launch_bounds__(256)
void combine_k(const float* __restrict__ mP, const float* __restrict__ sP,
               const float* __restrict__ OP, const int* __restrict__ top,
               ushort_t* __restrict__ ctxb)
{
    int tid = blockIdx.x * 256 + threadIdx.x;   // < 64*40*32
    int d  = tid & 31;
    int j  = (tid >> 5) % UU;
    int bh = tid / (UU * 32);
    float M = -3e38f;
    #pragma unroll
    for (int q = 0; q < NSL; ++q) M = fmaxf(M, mP[(bh * NSL + q) * UU + j]);
    float S = 0.f, O = 0.f;
    #pragma unroll
    for (int q = 0; q < NSL; ++q) {
        float w = __expf(mP[(bh * NSL + q) * UU + j] - M);
        S = fmaf(sP[(bh * NSL + q) * UU + j], w, S);
        O = fmaf(OP[((size_t)(bh * NSL + q) * UU + j) * 32 + d], w, O);
    }
    float u = O / S;
    int qi = top[bh * UU + j];
    int b = bh >> 3, hh = bh & 7;
    ctxb[(((size_t)(b * LL + qi)) << 8) + (hh << 5) + d] = f2b(u);
}

// ctx bf16 fill with vmean broadcast (2 elems/thread packed)
__global__ __launch_bounds__(256)
void fill2_k(ushort_t* __restrict__ ctxb, const float* __restrict__ vmean)
{
    int tid = blockIdx.x * 256 + threadIdx.x;
    int pr = tid & 127;
    int b  = tid >> 18;
    float v0 = vmean[(b << 8) + pr * 2];
    float v1 = vmean[(b << 8) + pr * 2 + 1];
    ((unsigned int*)ctxb)[tid] = (unsigned int)f2b(v0) | ((unsigned int)f2b(v1) << 16);
}

// h = LN(h + nx)*g + beta; wave-per-row, float4 IO, no barriers. grid 4096.
__global__ __launch_bounds__(256)
void addln_k(float* __restrict__ h, ushort_t* __restrict__ hb,
             const float* __restrict__ nx,
             const float* __restrict__ g, const float* __restrict__ beta)
{
    int lane = threadIdx.x & 63;
    int row  = blockIdx.x * 4 + (threadIdx.x >> 6);
    size_t i4 = (size_t)row * 64 + lane;
    float4 a = ((const float4*)h)[i4];
    float4 b = ((const float4*)nx)[i4];
    float4 xv = make_float4(a.x + b.x, a.y + b.y, a.z + b.z, a.w + b.w);
    float s  = xv.x + xv.y + xv.z + xv.w;
    float s2 = xv.x * xv.x + xv.y * xv.y + xv.z * xv.z + xv.w * xv.w;
    #pragma unroll
    for (int off = 32; off > 0; off >>= 1) {
        s  += __shfl_down(s, off, 64);
        s2 += __shfl_down(s2, off, 64);
    }
    float m   = __shfl(s, 0, 64) * (1.f / (float)DM);
    float var = __shfl(s2, 0, 64) * (1.f / (float)DM) - m * m;
    float inv = 1.0f / sqrtf(var + 1e-5f);
    float4 gg = ((const float4*)g)[lane];
    float4 be = ((const float4*)beta)[lane];
    float4 r;
    r.x = (xv.x - m) * inv * gg.x + be.x;
    r.y = (xv.y - m) * inv * gg.y + be.y;
    r.z = (xv.z - m) * inv * gg.z + be.z;
    r.w = (xv.w - m) * inv * gg.w + be.w;
    ((float4*)h)[i4] = r;
    unsigned int lo = f2b(r.x) | ((unsigned int)f2b(r.y) << 16);
    unsigned int hi = f2b(r.z) | ((unsigned int)f2b(r.w) << 16);
    ((uint2*)hb)[i4] = make_uint2(lo, hi);
}

__global__ __launch_bounds__(512)
void head_k(const float* __restrict__ h, const float* __restrict__ w1,
            const float* __restrict__ b1, const float* __restrict__ w2,
            const float* __restrict__ b2, float* __restrict__ out)
{
    int t = threadIdx.x;
    int b = t >> 6, j = t & 63;
    const float* hr = h + ((size_t)(b * LL + (LL - 1))) * DM;
    float s = 0.f;
    for (int kk = 0; kk < DM; ++kk) s = fmaf(hr[kk], w1[kk * 64 + j], s);
    s += b1[j];
    s = s > 0.f ? s : 0.f;
    float contrib = s * w2[j];
    #pragma unroll
    for (int off = 32; off > 0; off >>= 1) contrib += __shfl_down(contrib, off);
    if (j == 0) out[b] = contrib + b2[0];
}

extern "C" void kernel_launch(void* const* d_in, const int* in_sizes, int n_in,
                              void* d_out, int out_size, void* d_ws, size_t ws_size,
                              hipStream_t stream)
{
    const float* x    = (const float*)d_in[0];
    const int*   idx  = (const int*)  d_in[1];
    const float* w_in = (const float*)d_in[2];
    const float* b_in = (const float*)d_in[3];
    const float* wq   = (const float*)d_in[4];
    const float* bq   = (const float*)d_in[5];
    const float* wk   = (const float*)d_in[6];
    const float* bk   = (const float*)d_in[7];
    const float* wv   = (const float*)d_in[8];
    const float* bv   = (const float*)d_in[9];
    const float* wo   = (const float*)d_in[10];
    const float* bo   = (const float*)d_in[11];
    const float* wf1  = (const float*)d_in[12];
    const float* bf1  = (const float*)d_in[13];
    const float* wf2  = (const float*)d_in[14];
    const float* bf2  = (const float*)d_in[15];
    const float* g1   = (const float*)d_in[16];
    const float* be1  = (const float*)d_in[17];
    const float* g2   = (const float*)d_in[18];
    const float* be2  = (const float*)d_in[19];
    const float* wfc1 = (const float*)d_in[20];
    const float* bfc1 = (const float*)d_in[21];
    const float* wfc2 = (const float*)d_in[22];
    const float* bfc2 = (const float*)d_in[23];
    float* out = (float*)d_out;

    float* ws = (float*)d_ws;
    float*    h     = ws;                          // 4194304
    float*    qkv   = ws + 4194304;                // 12582912
    float*    qb    = qkv;
    float*    kb    = qkv + 4194304;
    float*    vb    = qkv + 8388608;
    float*    newxF = ws + 16777216;               // 4194304 (sub-aliased)
    ushort_t* kb16  = (ushort_t*)newxF;            //   [0, 2097152) floats
    float*    pm    = newxF + 2097152;             //   [2097152, 2621440)
    float*    psum  = newxF + 2621440;             //   [2621440, 3145728)
    float*    candv = newxF + 3145728;             //   [3145728, 3166208)
    int*      candi = (int*)(newxF + 3166208);     //   [3166208, 3186688)
    float*    vmeP  = newxF + 3186688;             //   [3186688, 3203072)
    float*    OP    = newxF + 2097152;             //   aliases pm/psum (post-topk)
    float*    mP    = newxF + 2752512;             //   20480 (post-topk)
    float*    sP    = newxF + 2772992;             //   20480 (post-topk)
    ushort_t* xb16  = (ushort_t*)(ws + 20971520);  // 262144 floats worth
    float*    vme   = ws + 21233664;               // 2048
    int*      top   = (int*)(ws + 21235712);       // 2560
    ushort_t* hb    = (ushort_t*)(ws + 21238272);  // 2097152 floats worth
    ushort_t* wqkvT = (ushort_t*)(ws + 23335424);  // 196608 floats worth
    ushort_t* woT   = (ushort_t*)(ws + 23532032);
    ushort_t* wf1T  = (ushort_t*)(ws + 23597568);
    ushort_t* wf2T  = (ushort_t*)(ws + 23859712);
    ushort_t* w_inT = (ushort_t*)(ws + 24121856);
    float*    bqkv  = ws + 24125952;
    ushort_t* ctxb  = (ushort_t*)qkv;              // aliases dead q
    ushort_t* ffbb  = (ushort_t*)(qkv + 2097152);  // aliases dead q/k/v

    dim3 blk(256);

    preproc_k<<<dim3(2062), blk, 0, stream>>>(
        wq, wk, wv, wo, wf1, wf2, w_in, bq, bk, bv, x,
        wqkvT, woT, wf1T, wf2T, w_inT, bqkv, xb16);

    gemm_mfma<0,3><<<dim3(BL/128, 2), blk, 0, stream>>>(
        xb16, w_inT, b_in, (void*)h, (void*)hb, BL, DM, 32);

    for (int i = 0; i < 2; ++i) {
        gemm_mfma<0,1><<<dim3(BL/128, 6), blk, 0, stream>>>(
            hb, wqkvT + (size_t)i*768*256, bqkv + i*768, (void*)qkv, (void*)kb16,
            BL, 768, DM);

        metric_k<<<dim3(2048), blk, 0, stream>>>(qb, kb16, idx + (size_t)i*LL*SS, pm, psum);
        topk1_k<<<dim3(128), blk, 0, stream>>>(pm, psum, candv, candi);
        topk2_k<<<dim3(BB*NH), blk, 0, stream>>>(candv, candi, top);
        vmeanp_k<<<dim3(512), blk, 0, stream>>>(vb, vmeP);
        vfin_k<<<dim3(8), blk, 0, stream>>>(vmeP, vme);
        attnupd_k<<<dim3(BB*NH*NSL), blk, 0, stream>>>(qb, kb, vb, top, mP, sP, OP);

        fill2_k<<<dim3(BL*DM/512), blk, 0, stream>>>(ctxb, vme);
        combine_k<<<dim3(BB*NH*UU*DH/256), blk, 0, stream>>>(mP, sP, OP, top, ctxb);

        gemm64_k<<<dim3(BL/64, 2), blk, 0, stream>>>(
            ctxb, woT + (size_t)i*256*256, bo + i*DM, newxF, BL, DM, DM);
        addln_k<<<dim3(BL/4), blk, 0, stream>>>(h, hb, newxF, g1 + i*DM, be1 + i*DM);

        gemm_mfma<1,2><<<dim3(BL/128, 8), blk, 0, stream>>>(
            hb, wf1T + (size_t)i*1024*256, bf1 + i*DFF, (void*)ffbb, nullptr, BL, DFF, DM);
        gemm64_k<<<dim3(BL/64, 2), blk, 0, stream>>>(
            ffbb, wf2T + (size_t)i*256*1024, bf2 + i*DM, newxF, BL, DM, DFF);
        addln_k<<<dim3(BL/4), blk, 0, stream>>>(h, hb, newxF, g2 + i*DM, be2 + i*DM);
    }

    head_k<<<dim3(1), dim3(512), 0, stream>>>(h, wfc1, bfc1, wfc2, bfc2, out);
}

// Round 8
// 539.356 us; speedup vs baseline: 2.7831x; 1.0513x over previous
//
#include <hip/hip_runtime.h>
#include <math.h>

#define BB 8
#define LL 2048
#define DM 256
#define NH 8
#define DH 32
#define DFF 1024
#define SS 40
#define UU 40
#define BL (BB*LL)   // 16384
#define NSL 8        // attnupd L-slices per (b,h)

typedef unsigned short ushort_t;
typedef __attribute__((ext_vector_type(8))) short short8;
typedef __attribute__((ext_vector_type(4))) float f32x4;

__device__ inline ushort_t f2b(float f)
{
    unsigned int u = __float_as_uint(f);
    u += 0x7fff + ((u >> 16) & 1);      // round-to-nearest-even
    return (ushort_t)(u >> 16);
}

__device__ inline void gload16(const void* g, const void* l)
{
    __builtin_amdgcn_global_load_lds(
        (const __attribute__((address_space(1))) unsigned int*)g,
        (__attribute__((address_space(3))) unsigned int*)l, 16, 0, 0);
}

// ---------------------------------------------------------------------------
// bf16 MFMA GEMM, m97 structure. 128x128 tile, BK=32, 256 thr.
// OUT_MODE: 0 fp32 RM | 1 QKV scatter (fp32 q,k,v BHLD + bf16 kT[l][bh][d])
//           2 bf16 RM | 3 fp32 RM + bf16 RM into aux
// ---------------------------------------------------------------------------
template<int RELU, int OUT_MODE>
__global__ __launch_bounds__(256)
void gemm_mfma(const ushort_t* __restrict__ A, const ushort_t* __restrict__ Bt,
               const float* __restrict__ bias, void* __restrict__ Cout,
               void* __restrict__ aux, int M, int N, int K)
{
    __shared__ ushort_t Asl[128 * 32];
    __shared__ ushort_t Bsl[128 * 32];

    const int t    = threadIdx.x;
    const int lane = t & 63;
    const int wv   = t >> 6;
    const int row0 = blockIdx.x * 128;
    const int col0 = blockIdx.y * 128;
    const int wr   = (wv >> 1) * 64;
    const int wc   = (wv & 1) * 64;
    const int quad = lane >> 4;
    const int l16  = lane & 15;

    f32x4 acc[4][4];
    #pragma unroll
    for (int i = 0; i < 4; ++i)
        #pragma unroll
        for (int j = 0; j < 4; ++j)
            acc[i][j] = 0.f;

    for (int k0 = 0; k0 < K; k0 += 32) {
        __syncthreads();
        #pragma unroll
        for (int r = 0; r < 2; ++r) {
            int g = r * 256 + t;
            const ushort_t* ga = A  + (size_t)(row0 + (g >> 2)) * K + k0 + (g & 3) * 8;
            const ushort_t* gb = Bt + (size_t)(col0 + (g >> 2)) * K + k0 + (g & 3) * 8;
            int lbase = (r * 256 + wv * 64) * 16;
            gload16(ga, (const char*)Asl + lbase);
            gload16(gb, (const char*)Bsl + lbase);
        }
        __syncthreads();

        short8 af[4], bfr[4];
        #pragma unroll
        for (int mi = 0; mi < 4; ++mi)
            af[mi] = *(const short8*)&Asl[(wr + mi * 16 + l16) * 32 + quad * 8];
        #pragma unroll
        for (int ni = 0; ni < 4; ++ni)
            bfr[ni] = *(const short8*)&Bsl[(wc + ni * 16 + l16) * 32 + quad * 8];
        #pragma unroll
        for (int mi = 0; mi < 4; ++mi)
            #pragma unroll
            for (int ni = 0; ni < 4; ++ni)
                acc[mi][ni] = __builtin_amdgcn_mfma_f32_16x16x32_bf16(
                    af[mi], bfr[ni], acc[mi][ni], 0, 0, 0);
    }

    #pragma unroll
    for (int mi = 0; mi < 4; ++mi) {
        #pragma unroll
        for (int ni = 0; ni < 4; ++ni) {
            int col = col0 + wc + ni * 16 + l16;
            float bb = bias[col];
            #pragma unroll
            for (int r = 0; r < 4; ++r) {
                int row = row0 + wr + mi * 16 + quad * 4 + r;
                float v = acc[mi][ni][r] + bb;
                if (RELU) v = v > 0.f ? v : 0.f;
                if (OUT_MODE == 0) {
                    ((float*)Cout)[(size_t)row * N + col] = v;
                } else if (OUT_MODE == 1) {
                    int tensor = col >> 8;          // 0=q 1=k 2=v
                    int c2 = col & 255;
                    int b  = row >> 11, l = row & (LL - 1);
                    int hh = c2 >> 5,  dh = c2 & 31;
                    int bh = b * NH + hh;
                    size_t bi = (((size_t)bh * LL + l) << 5) + dh;
                    ((float*)Cout)[(size_t)tensor * (BB*NH*LL*DH) + bi] = v;
                    if (tensor == 1)   // kT[l][bh][d] bf16 for metric
                        ((ushort_t*)aux)[(((size_t)l << 6) + bh) * 32 + dh] = f2b(v);
                } else if (OUT_MODE == 2) {
                    ((ushort_t*)Cout)[(size_t)row * N + col] = f2b(v);
                } else {
                    ((float*)Cout)[(size_t)row * N + col] = v;
                    ((ushort_t*)aux)[(size_t)row * N + col] = f2b(v);
                }
            }
        }
    }
}

// ---------------------------------------------------------------------------
// 64x128-tile MFMA GEMM (fp32 out) — for N=256 GEMMs: 2x the blocks/CU.
// ---------------------------------------------------------------------------
__global__ __launch_bounds__(256)
void gemm64_k(const ushort_t* __restrict__ A, const ushort_t* __restrict__ Bt,
              const float* __restrict__ bias, float* __restrict__ Cout,
              int M, int N, int K)
{
    __shared__ ushort_t Asl[64 * 32];
    __shared__ ushort_t Bsl[128 * 32];

    const int t    = threadIdx.x;
    const int lane = t & 63;
    const int wv   = t >> 6;
    const int row0 = blockIdx.x * 64;
    const int col0 = blockIdx.y * 128;
    const int wc   = wv * 32;
    const int quad = lane >> 4;
    const int l16  = lane & 15;

    f32x4 acc[4][2];
    #pragma unroll
    for (int i = 0; i < 4; ++i) { acc[i][0] = 0.f; acc[i][1] = 0.f; }

    for (int k0 = 0; k0 < K; k0 += 32) {
        __syncthreads();
        {
            const ushort_t* ga = A + (size_t)(row0 + (t >> 2)) * K + k0 + (t & 3) * 8;
            gload16(ga, (const char*)Asl + wv * 64 * 16);
        }
        #pragma unroll
        for (int r = 0; r < 2; ++r) {
            int g = r * 256 + t;
            const ushort_t* gb = Bt + (size_t)(col0 + (g >> 2)) * K + k0 + (g & 3) * 8;
            gload16(gb, (const char*)Bsl + (r * 256 + wv * 64) * 16);
        }
        __syncthreads();

        short8 af[4], bfr[2];
        #pragma unroll
        for (int mi = 0; mi < 4; ++mi)
            af[mi] = *(const short8*)&Asl[(mi * 16 + l16) * 32 + quad * 8];
        #pragma unroll
        for (int ni = 0; ni < 2; ++ni)
            bfr[ni] = *(const short8*)&Bsl[(wc + ni * 16 + l16) * 32 + quad * 8];
        #pragma unroll
        for (int mi = 0; mi < 4; ++mi)
            #pragma unroll
            for (int ni = 0; ni < 2; ++ni)
                acc[mi][ni] = __builtin_amdgcn_mfma_f32_16x16x32_bf16(
                    af[mi], bfr[ni], acc[mi][ni], 0, 0, 0);
    }

    #pragma unroll
    for (int mi = 0; mi < 4; ++mi) {
        #pragma unroll
        for (int ni = 0; ni < 2; ++ni) {
            int col = col0 + wc + ni * 16 + l16;
            float bb = bias[col];
            #pragma unroll
            for (int r = 0; r < 4; ++r) {
                int row = row0 + mi * 16 + quad * 4 + r;
                Cout[(size_t)row * N + col] = acc[mi][ni][r] + bb;
            }
        }
    }
}

// ---------------------------------------------------------------------------
// fused preproc: all weight transposes+cvt, bias pack, x cvt in ONE dispatch.
// ---------------------------------------------------------------------------
__device__ inline void tcvt_dev(float (*tile)[33], const float* __restrict__ src,
                                ushort_t* __restrict__ dst, int K, int N,
                                int matStride, int bi)
{
    int tilesN = N >> 5;
    int tpm = (K >> 5) * tilesN;
    int m   = bi / tpm;
    int tid = bi % tpm;
    int k0 = (tid / tilesN) << 5, n0 = (tid % tilesN) << 5;
    const float* s = src + (size_t)m * K * N;
    ushort_t*    d = dst + (size_t)m * matStride;
    int r = threadIdx.x >> 5, c = threadIdx.x & 31;
    #pragma unroll
    for (int i = 0; i < 4; ++i)
        tile[r + 8 * i][c] = s[(size_t)(k0 + r + 8 * i) * N + n0 + c];
    __syncthreads();
    #pragma unroll
    for (int i = 0; i < 4; ++i)
        d[(size_t)(n0 + r + 8 * i) * K + k0 + c] = f2b(tile[c][r + 8 * i]);
}

__global__ __launch_bounds__(256)
void preproc_k(const float* __restrict__ wq, const float* __restrict__ wk,
               const float* __restrict__ wv, const float* __restrict__ wo,
               const float* __restrict__ wf1, const float* __restrict__ wf2,
               const float* __restrict__ w_in,
               const float* __restrict__ bq, const float* __restrict__ bk,
               const float* __restrict__ bv, const float* __restrict__ x,
               ushort_t* __restrict__ wqkvT, ushort_t* __restrict__ woT,
               ushort_t* __restrict__ wf1T, ushort_t* __restrict__ wf2T,
               ushort_t* __restrict__ w_inT, float* __restrict__ bqkv,
               ushort_t* __restrict__ xb16)
{
    __shared__ float tile[32][33];
    int b = blockIdx.x;
    if (b < 512) {
        int which = b >> 7, lb = b & 127;
        const float* src = which == 0 ? wq : which == 1 ? wk : which == 2 ? wv : wo;
        ushort_t* dst = which == 0 ? wqkvT : which == 1 ? wqkvT + 65536
                       : which == 2 ? wqkvT + 131072 : woT;
        int stride = which == 3 ? 65536 : 768 * 256;
        tcvt_dev(tile, src, dst, DM, DM, stride, lb);
    } else if (b < 1024) {
        tcvt_dev(tile, wf1, wf1T, DM, DFF, 1024 * 256, b - 512);
    } else if (b < 1536) {
        tcvt_dev(tile, wf2, wf2T, DFF, DM, 256 * 1024, b - 1024);
    } else if (b < 1544) {
        tcvt_dev(tile, w_in, w_inT, 32, DM, 256 * 32, b - 1536);
    } else if (b < 1550) {
        int t = (b - 1544) * 256 + threadIdx.x;
        int i = t / 768, j = t % 768;
        const float* s = j < 256 ? bq : (j < 512 ? bk : bv);
        bqkv[t] = s[i * 256 + (j & 255)];
    } else {
        int tid = (b - 1550) * 256 + threadIdx.x;
        float4 v = ((const float4*)x)[tid];
        unsigned int lo = f2b(v.x) | ((unsigned int)f2b(v.y) << 16);
        unsigned int hi = f2b(v.z) | ((unsigned int)f2b(v.w) << 16);
        ((uint2*)xb16)[tid] = make_uint2(lo, hi);
    }
}

// ---------------------------------------------------------------------------
// metric v3: lane = bh, wave = one query position l. kT[l][bh][d] reads are
// fully coalesced (lane-stride 64 B). q row in registers. grid 512 x 256.
// ---------------------------------------------------------------------------
__global__ __launch_bounds__(256)
void metric2_k(const float* __restrict__ qb, const ushort_t* __restrict__ kT,
               const int* __restrict__ idx, float* __restrict__ Mout)
{
    __shared__ float mst[64][5];
    int t = threadIdx.x;
    int w = t >> 6, lane = t & 63;
    int l = blockIdx.x * 4 + w;

    const float4* qr = (const float4*)(qb + ((size_t)(lane * LL + l) << 5));
    float4 q[8];
    #pragma unroll
    for (int i = 0; i < 8; ++i) q[i] = qr[i];

    int r40 = idx[l * SS + (lane < SS ? lane : SS - 1)];

    float mx = -3e38f, sm = 0.f;
    for (int s = 0; s < SS; ++s) {
        int r = __shfl(r40, s, 64);
        const uint4* kr = (const uint4*)(kT + (((size_t)r << 6) + lane) * 32);
        float d = 0.f;
        #pragma unroll
        for (int ww = 0; ww < 4; ++ww) {
            uint4 kv = kr[ww];
            float4 qa = q[2 * ww], qb2 = q[2 * ww + 1];
            d = fmaf(__uint_as_float(kv.x << 16),         qa.x, d);
            d = fmaf(__uint_as_float(kv.x & 0xffff0000u), qa.y, d);
            d = fmaf(__uint_as_float(kv.y << 16),         qa.z, d);
            d = fmaf(__uint_as_float(kv.y & 0xffff0000u), qa.w, d);
            d = fmaf(__uint_as_float(kv.z << 16),         qb2.x, d);
            d = fmaf(__uint_as_float(kv.z & 0xffff0000u), qb2.y, d);
            d = fmaf(__uint_as_float(kv.w << 16),         qb2.z, d);
            d = fmaf(__uint_as_float(kv.w & 0xffff0000u), qb2.w, d);
        }
        mx = fmaxf(mx, d);
        sm += d;
    }
    mst[lane][w] = mx - sm * (1.0f / (float)LL);
    __syncthreads();

    int bh = t >> 2, ls = t & 3;
    Mout[(size_t)bh * LL + blockIdx.x * 4 + ls] = mst[bh][ls];
}

// ---------------------------------------------------------------------------
// topk stage 1: wave-synchronous per-slice top-40 (no barriers). grid 128.
// ---------------------------------------------------------------------------
__global__ __launch_bounds__(256)
void topk1_k(const float* __restrict__ Mout,
             float* __restrict__ cand_v, int* __restrict__ cand_i)
{
    int lane = threadIdx.x & 63;
    int slg  = blockIdx.x * 4 + (threadIdx.x >> 6);   // 0..511
    int bh   = slg >> 3;
    int l0   = (slg & 7) << 8;

    float v[4];
    #pragma unroll
    for (int i = 0; i < 4; ++i)
        v[i] = Mout[(size_t)bh * LL + l0 + i * 64 + lane];

    for (int r = 0; r < UU; ++r) {
        float bv = -3e38f; int bi = 1 << 30;
        #pragma unroll
        for (int i = 0; i < 4; ++i) {
            int idx = l0 + i * 64 + lane;
            if (v[i] > bv || (v[i] == bv && idx < bi)) { bv = v[i]; bi = idx; }
        }
        #pragma unroll
        for (int off = 32; off > 0; off >>= 1) {
            float ov = __shfl_down(bv, off, 64);
            int   oi = __shfl_down(bi, off, 64);
            if (ov > bv || (ov == bv && oi < bi)) { bv = ov; bi = oi; }
        }
        bv = __shfl(bv, 0, 64);
        bi = __shfl(bi, 0, 64);
        if (lane == 0) {
            cand_v[slg * UU + r] = bv;
            cand_i[slg * UU + r] = bi;
        }
        int rel = bi - l0;
        if ((rel & 63) == lane) v[rel >> 6] = -3e38f;
    }
}

// topk stage 2: rank-select top-40 from 320 candidates per bh.
__global__ __launch_bounds__(256)
void topk2_k(const float* __restrict__ cand_v, const int* __restrict__ cand_i,
             int* __restrict__ top)
{
    __shared__ float cv[320];
    __shared__ int   ci[320];
    int bh = blockIdx.x, t = threadIdx.x;
    for (int i = t; i < 320; i += 256) {
        cv[i] = cand_v[bh * 320 + i];
        ci[i] = cand_i[bh * 320 + i];
    }
    __syncthreads();
    for (int c = t; c < 320; c += 256) {
        float mv = cv[c]; int mi = ci[c];
        int rank = 0;
        for (int j = 0; j < 320; ++j)
            rank += (cv[j] > mv) || (cv[j] == mv && ci[j] < mi);
        if (rank < UU) top[bh * UU + rank] = mi;
    }
}

// vmean partials: grid 512 (bh x 8 slices)
__global__ __launch_bounds__(256)
void vmeanp_k(const float* __restrict__ vb, float* __restrict__ vmeP)
{
    __shared__ float red[8][32];
    int blk = blockIdx.x;
    int bh = blk >> 3, sl = blk & 7;
    int t = threadIdx.x;
    int d = t & 31, part = t >> 5;
    const float* base = vb + ((size_t)(bh * LL + sl * 256 + part * 32) << 5);
    float s = 0.f;
    #pragma unroll 8
    for (int i = 0; i < 32; ++i) s += base[(i << 5) + d];
    red[part][d] = s;
    __syncthreads();
    if (t < 32) {
        float tot = 0.f;
        #pragma unroll
        for (int p = 0; p < 8; ++p) tot += red[p][t];
        vmeP[blk * 32 + t] = tot;
    }
}

__global__ __launch_bounds__(256)
void vfin_k(const float* __restrict__ vmeP, float* __restrict__ vme)
{
    int tid = blockIdx.x * 256 + threadIdx.x;   // < 2048
    int bh = tid >> 5, d = tid & 31;
    float s = 0.f;
    #pragma unroll
    for (int sl = 0; sl < 8; ++sl) s += vmeP[(bh * 8 + sl) * 32 + d];
    vme[tid] = s * (1.f / (float)LL);
}

// ---------------------------------------------------------------------------
// attnupd: block = bh*NSL + slice (512 blocks), 256 l per slice.
// ---------------------------------------------------------------------------
__global__ __launch_bounds__(256)
void attnupd_k(const float* __restrict__ qb, const float* __restrict__ kb,
               const float* __restrict__ vb, const int* __restrict__ top,
               float* __restrict__ mP, float* __restrict__ sP,
               float* __restrict__ OP)
{
    __shared__ float qs[UU * 32];        // 5 KB
    __shared__ float sc[UU * 256];       // 40 KB
    __shared__ float msh[UU];

    int blk = blockIdx.x;
    int sl  = blk & (NSL - 1);
    int bh  = blk >> 3;
    int t   = threadIdx.x;
    int l0  = sl << 8;

    for (int i = t; i < UU * 32; i += 256) {
        int j = i >> 5, dd = i & 31;
        qs[i] = qb[((size_t)(bh * LL + top[bh * UU + j]) << 5) + dd];
    }

    const float4* kr = (const float4*)(kb + ((size_t)(bh * LL + l0 + t) << 5));
    float4 k4[8];
    #pragma unroll
    for (int i = 0; i < 8; ++i) k4[i] = kr[i];
    __syncthreads();

    const float scale = 0.17677669529663687f;   // 1/sqrt(32)
    #pragma unroll 4
    for (int j = 0; j < UU; ++j) {
        float ds = 0.f;
        #pragma unroll
        for (int i = 0; i < 8; ++i) {
            float4 qv = *(const float4*)&qs[j * 32 + 4 * i];   // broadcast
            ds = fmaf(qv.x, k4[i].x, ds);
            ds = fmaf(qv.y, k4[i].y, ds);
            ds = fmaf(qv.z, k4[i].z, ds);
            ds = fmaf(qv.w, k4[i].w, ds);
        }
        sc[j * 256 + t] = ds * scale;
    }
    __syncthreads();

    int j8 = t >> 5, d = t & 31;
    #pragma unroll
    for (int g = 0; g < 5; ++g) {
        int j = g * 8 + j8;
        float4 a = *(const float4*)&sc[j * 256 + 4 * d];
        float4 b = *(const float4*)&sc[j * 256 + 128 + 4 * d];
        float m = fmaxf(fmaxf(fmaxf(a.x, a.y), fmaxf(a.z, a.w)),
                        fmaxf(fmaxf(b.x, b.y), fmaxf(b.z, b.w)));
        #pragma unroll
        for (int off = 16; off > 0; off >>= 1)
            m = fmaxf(m, __shfl_down(m, off, 64));
        if (d == 0) msh[j] = m;
    }
    __syncthreads();

    #pragma unroll 8
    for (int i = t; i < UU * 256; i += 256) {
        int j = i >> 8;
        sc[i] = __expf(sc[i] - msh[j]);
    }
    __syncthreads();

    int pq = bh * NSL + sl;

    #pragma unroll
    for (int g = 0; g < 5; ++g) {
        int j = g * 8 + j8;
        float4 a = *(const float4*)&sc[j * 256 + 4 * d];
        float4 b = *(const float4*)&sc[j * 256 + 128 + 4 * d];
        float s = a.x + a.y + a.z + a.w + b.x + b.y + b.z + b.w;
        #pragma unroll
        for (int off = 16; off > 0; off >>= 1)
            s += __shfl_down(s, off, 64);
        if (d == 0) { sP[pq * UU + j] = s; mP[pq * UU + j] = msh[j]; }
    }

    const float* vbase = vb + ((size_t)(bh * LL + l0) << 5) + d;
    float acc[5] = {0.f, 0.f, 0.f, 0.f, 0.f};
    #pragma unroll 4
    for (int i = 0; i < 64; ++i) {
        float v0 = vbase[(4 * i + 0) << 5];
        float v1 = vbase[(4 * i + 1) << 5];
        float v2 = vbase[(4 * i + 2) << 5];
        float v3 = vbase[(4 * i + 3) << 5];
        #pragma unroll
        for (int g = 0; g < 5; ++g) {
            float4 e4 = *(const float4*)&sc[(g * 8 + j8) * 256 + 4 * i];
            acc[g] = fmaf(e4.x, v0, acc[g]);
            acc[g] = fmaf(e4.y, v1, acc[g]);
            acc[g] = fmaf(e4.z, v2, acc[g]);
            acc[g] = fmaf(e4.w, v3, acc[g]);
        }
    }
    #pragma unroll
    for (int g = 0; g < 5; ++g)
        OP[((size_t)pq * UU + g * 8 + j8) * 32 + d] = acc[g];
}

// merge NSL slice-partials, normalize, scatter bf16 into ctx
__global__ __launch_bounds__(256)
void combine_k(const float* __restrict__ mP, const float* __restrict__ sP,
               const float* __restrict__ OP, const int* __restrict__ top,
               ushort_t* __restrict__ ctxb)
{
    int tid = blockIdx.x * 256 + threadIdx.x;   // < 64*40*32
    int d  = tid & 31;
    int j  = (tid >> 5) % UU;
    int bh = tid / (UU * 32);
    float M = -3e38f;
    #pragma unroll
    for (int q = 0; q < NSL; ++q) M = fmaxf(M, mP[(bh * NSL + q) * UU + j]);
    float S = 0.f, O = 0.f;
    #pragma unroll
    for (int q = 0; q < NSL; ++q) {
        float w = __expf(mP[(bh * NSL + q) * UU + j] - M);
        S = fmaf(sP[(bh * NSL + q) * UU + j], w, S);
        O = fmaf(OP[((size_t)(bh * NSL + q) * UU + j) * 32 + d], w, O);
    }
    float u = O / S;
    int qi = top[bh * UU + j];
    int b = bh >> 3, hh = bh & 7;
    ctxb[(((size_t)(b * LL + qi)) << 8) + (hh << 5) + d] = f2b(u);
}

// ctx bf16 fill with vmean broadcast (2 elems/thread packed)
__global__ __launch_bounds__(256)
void fill2_k(ushort_t* __restrict__ ctxb, const float* __restrict__ vmean)
{
    int tid = blockIdx.x * 256 + threadIdx.x;
    int pr = tid & 127;
    int b  = tid >> 18;
    float v0 = vmean[(b << 8) + pr * 2];
    float v1 = vmean[(b << 8) + pr * 2 + 1];
    ((unsigned int*)ctxb)[tid] = (unsigned int)f2b(v0) | ((unsigned int)f2b(v1) << 16);
}

// h = LN(h + nx)*g + beta; wave-per-row, float4 IO, no barriers. grid 4096.
__global__ __launch_bounds__(256)
void addln_k(float* __restrict__ h, ushort_t* __restrict__ hb,
             const float* __restrict__ nx,
             const float* __restrict__ g, const float* __restrict__ beta)
{
    int lane = threadIdx.x & 63;
    int row  = blockIdx.x * 4 + (threadIdx.x >> 6);
    size_t i4 = (size_t)row * 64 + lane;
    float4 a = ((const float4*)h)[i4];
    float4 b = ((const float4*)nx)[i4];
    float4 xv = make_float4(a.x + b.x, a.y + b.y, a.z + b.z, a.w + b.w);
    float s  = xv.x + xv.y + xv.z + xv.w;
    float s2 = xv.x * xv.x + xv.y * xv.y + xv.z * xv.z + xv.w * xv.w;
    #pragma unroll
    for (int off = 32; off > 0; off >>= 1) {
        s  += __shfl_down(s, off, 64);
        s2 += __shfl_down(s2, off, 64);
    }
    float m   = __shfl(s, 0, 64) * (1.f / (float)DM);
    float var = __shfl(s2, 0, 64) * (1.f / (float)DM) - m * m;
    float inv = 1.0f / sqrtf(var + 1e-5f);
    float4 gg = ((const float4*)g)[lane];
    float4 be = ((const float4*)beta)[lane];
    float4 r;
    r.x = (xv.x - m) * inv * gg.x + be.x;
    r.y = (xv.y - m) * inv * gg.y + be.y;
    r.z = (xv.z - m) * inv * gg.z + be.z;
    r.w = (xv.w - m) * inv * gg.w + be.w;
    ((float4*)h)[i4] = r;
    unsigned int lo = f2b(r.x) | ((unsigned int)f2b(r.y) << 16);
    unsigned int hi = f2b(r.z) | ((unsigned int)f2b(r.w) << 16);
    ((uint2*)hb)[i4] = make_uint2(lo, hi);
}

__global__ __launch_bounds__(512)
void head_k(const float* __restrict__ h, const float* __restrict__ w1,
            const float* __restrict__ b1, const float* __restrict__ w2,
            const float* __restrict__ b2, float* __restrict__ out)
{
    int t = threadIdx.x;
    int b = t >> 6, j = t & 63;
    const float* hr = h + ((size_t)(b * LL + (LL - 1))) * DM;
    float s = 0.f;
    for (int kk = 0; kk < DM; ++kk) s = fmaf(hr[kk], w1[kk * 64 + j], s);
    s += b1[j];
    s = s > 0.f ? s : 0.f;
    float contrib = s * w2[j];
    #pragma unroll
    for (int off = 32; off > 0; off >>= 1) contrib += __shfl_down(contrib, off);
    if (j == 0) out[b] = contrib + b2[0];
}

extern "C" void kernel_launch(void* const* d_in, const int* in_sizes, int n_in,
                              void* d_out, int out_size, void* d_ws, size_t ws_size,
                              hipStream_t stream)
{
    const float* x    = (const float*)d_in[0];
    const int*   idx  = (const int*)  d_in[1];
    const float* w_in = (const float*)d_in[2];
    const float* b_in = (const float*)d_in[3];
    const float* wq   = (const float*)d_in[4];
    const float* bq   = (const float*)d_in[5];
    const float* wk   = (const float*)d_in[6];
    const float* bk   = (const float*)d_in[7];
    const float* wv   = (const float*)d_in[8];
    const float* bv   = (const float*)d_in[9];
    const float* wo   = (const float*)d_in[10];
    const float* bo   = (const float*)d_in[11];
    const float* wf1  = (const float*)d_in[12];
    const float* bf1  = (const float*)d_in[13];
    const float* wf2  = (const float*)d_in[14];
    const float* bf2  = (const float*)d_in[15];
    const float* g1   = (const float*)d_in[16];
    const float* be1  = (const float*)d_in[17];
    const float* g2   = (const float*)d_in[18];
    const float* be2  = (const float*)d_in[19];
    const float* wfc1 = (const float*)d_in[20];
    const float* bfc1 = (const float*)d_in[21];
    const float* wfc2 = (const float*)d_in[22];
    const float* bfc2 = (const float*)d_in[23];
    float* out = (float*)d_out;

    float* ws = (float*)d_ws;
    float*    h     = ws;                          // [0, 4194304)
    float*    qkv   = ws + 4194304;                // [4194304, 16777216)
    float*    qb    = qkv;
    float*    kb    = qkv + 4194304;
    float*    vb    = qkv + 8388608;
    // newxF region (4194304 floats): GEMM fp32 out; hosts attention-phase
    // scratch (all consumed before gemm64 writes newxF each layer).
    float*    newxF = ws + 16777216;
    ushort_t* kT16  = (ushort_t*)newxF;            //   fl [0, 2097152): kT[l][bh][d] bf16
    float*    Mbuf  = newxF + 2097152;             //   fl [2097152, 2228224)
    float*    candv = newxF + 2228224;             //   20480
    int*      candi = (int*)(newxF + 2248704);     //   20480
    float*    vmeP  = newxF + 2269184;             //   16384
    float*    OP    = newxF + 2285568;             //   655360
    float*    mP    = newxF + 2940928;             //   20480
    float*    sP    = newxF + 2961408;             //   20480 (ends 2981888 < 4194304)
    // long-lived scratch — sizes in FLOATS (ushort counts halved!):
    float*    scr   = ws + 20971520;
    ushort_t* xb16  = (ushort_t*)scr;              //   fl [0, 262144)        (524288 us)
    float*    vme   = scr + 262144;                //   fl [262144, 264192)
    int*      top   = (int*)(scr + 264192);        //   fl [264192, 266752)
    ushort_t* hb    = (ushort_t*)(scr + 266752);   //   fl [266752, 2363904)  (4194304 us)
    ushort_t* wqkvT = (ushort_t*)(scr + 2363904);  //   fl [2363904, 2560512) (393216 us)
    ushort_t* woT   = (ushort_t*)(scr + 2560512);  //   fl [2560512, 2626048) (131072 us)
    ushort_t* wf1T  = (ushort_t*)(scr + 2626048);  //   fl [2626048, 2888192) (524288 us)
    ushort_t* wf2T  = (ushort_t*)(scr + 2888192);  //   fl [2888192, 3150336) (524288 us)
    ushort_t* w_inT = (ushort_t*)(scr + 3150336);  //   fl [3150336, 3154432) (8192 us)
    float*    bqkv  = scr + 3154432;               //   fl [3154432, 3155968)
    ushort_t* ctxb  = (ushort_t*)qkv;              // aliases dead q
    ushort_t* ffbb  = (ushort_t*)(qkv + 2097152);  // aliases dead q/k/v

    dim3 blk(256);

    preproc_k<<<dim3(2062), blk, 0, stream>>>(
        wq, wk, wv, wo, wf1, wf2, w_in, bq, bk, bv, x,
        wqkvT, woT, wf1T, wf2T, w_inT, bqkv, xb16);

    gemm_mfma<0,3><<<dim3(BL/128, 2), blk, 0, stream>>>(
        xb16, w_inT, b_in, (void*)h, (void*)hb, BL, DM, 32);

    for (int i = 0; i < 2; ++i) {
        gemm_mfma<0,1><<<dim3(BL/128, 6), blk, 0, stream>>>(
            hb, wqkvT + (size_t)i*768*256, bqkv + i*768, (void*)qkv, (void*)kT16,
            BL, 768, DM);

        metric2_k<<<dim3(512), blk, 0, stream>>>(qb, kT16, idx + (size_t)i*LL*SS, Mbuf);
        topk1_k<<<dim3(128), blk, 0, stream>>>(Mbuf, candv, candi);
        topk2_k<<<dim3(BB*NH), blk, 0, stream>>>(candv, candi, top);
        vmeanp_k<<<dim3(512), blk, 0, stream>>>(vb, vmeP);
        vfin_k<<<dim3(8), blk, 0, stream>>>(vmeP, vme);
        attnupd_k<<<dim3(BB*NH*NSL), blk, 0, stream>>>(qb, kb, vb, top, mP, sP, OP);

        fill2_k<<<dim3(BL*DM/512), blk, 0, stream>>>(ctxb, vme);
        combine_k<<<dim3(BB*NH*UU*DH/256), blk, 0, stream>>>(mP, sP, OP, top, ctxb);

        gemm64_k<<<dim3(BL/64, 2), blk, 0, stream>>>(
            ctxb, woT + (size_t)i*256*256, bo + i*DM, newxF, BL, DM, DM);
        addln_k<<<dim3(BL/4), blk, 0, stream>>>(h, hb, newxF, g1 + i*DM, be1 + i*DM);

        gemm_mfma<1,2><<<dim3(BL/128, 8), blk, 0, stream>>>(
            hb, wf1T + (size_t)i*1024*256, bf1 + i*DFF, (void*)ffbb, nullptr, BL, DFF, DM);
        gemm64_k<<<dim3(BL/64, 2), blk, 0, stream>>>(
            ffbb, wf2T + (size_t)i*256*1024, bf2 + i*DM, newxF, BL, DM, DFF);
        addln_k<<<dim3(BL/4), blk, 0, stream>>>(h, hb, newxF, g2 + i*DM, be2 + i*DM);
    }

    head_k<<<dim3(1), dim3(512), 0, stream>>>(h, wfc1, bfc1, wfc2, bfc2, out);
}

// Round 9
// 518.971 us; speedup vs baseline: 2.8924x; 1.0393x over previous
//
#include <hip/hip_runtime.h>
#include <math.h>

#define BB 8
#define LL 2048
#define DM 256
#define NH 8
#define DH 32
#define DFF 1024
#define SS 40
#define UU 40
#define BL (BB*LL)   // 16384
#define NSL 8        // attnupd L-slices per (b,h)

typedef unsigned short ushort_t;
typedef __attribute__((ext_vector_type(8))) short short8;
typedef __attribute__((ext_vector_type(4))) float f32x4;

__device__ inline ushort_t f2b(float f)
{
    unsigned int u = __float_as_uint(f);
    u += 0x7fff + ((u >> 16) & 1);      // round-to-nearest-even
    return (ushort_t)(u >> 16);
}

__device__ inline void gload16(const void* g, const void* l)
{
    __builtin_amdgcn_global_load_lds(
        (const __attribute__((address_space(1))) unsigned int*)g,
        (__attribute__((address_space(3))) unsigned int*)l, 16, 0, 0);
}

// ---------------------------------------------------------------------------
// bf16 MFMA GEMM, m97 structure. 128x128 tile, BK=32, 256 thr.
// OUT_MODE: 0 fp32 RM | 1 QKV scatter (fp32 q,k,v BHLD + bf16 kT[l][bh][d])
//           2 bf16 RM | 3 fp32 RM + bf16 RM into aux
// ---------------------------------------------------------------------------
template<int RELU, int OUT_MODE>
__global__ __launch_bounds__(256)
void gemm_mfma(const ushort_t* __restrict__ A, const ushort_t* __restrict__ Bt,
               const float* __restrict__ bias, void* __restrict__ Cout,
               void* __restrict__ aux, int M, int N, int K)
{
    __shared__ ushort_t Asl[128 * 32];
    __shared__ ushort_t Bsl[128 * 32];

    const int t    = threadIdx.x;
    const int lane = t & 63;
    const int wv   = t >> 6;
    const int row0 = blockIdx.x * 128;
    const int col0 = blockIdx.y * 128;
    const int wr   = (wv >> 1) * 64;
    const int wc   = (wv & 1) * 64;
    const int quad = lane >> 4;
    const int l16  = lane & 15;

    f32x4 acc[4][4];
    #pragma unroll
    for (int i = 0; i < 4; ++i)
        #pragma unroll
        for (int j = 0; j < 4; ++j)
            acc[i][j] = 0.f;

    for (int k0 = 0; k0 < K; k0 += 32) {
        __syncthreads();
        #pragma unroll
        for (int r = 0; r < 2; ++r) {
            int g = r * 256 + t;
            const ushort_t* ga = A  + (size_t)(row0 + (g >> 2)) * K + k0 + (g & 3) * 8;
            const ushort_t* gb = Bt + (size_t)(col0 + (g >> 2)) * K + k0 + (g & 3) * 8;
            int lbase = (r * 256 + wv * 64) * 16;
            gload16(ga, (const char*)Asl + lbase);
            gload16(gb, (const char*)Bsl + lbase);
        }
        __syncthreads();

        short8 af[4], bfr[4];
        #pragma unroll
        for (int mi = 0; mi < 4; ++mi)
            af[mi] = *(const short8*)&Asl[(wr + mi * 16 + l16) * 32 + quad * 8];
        #pragma unroll
        for (int ni = 0; ni < 4; ++ni)
            bfr[ni] = *(const short8*)&Bsl[(wc + ni * 16 + l16) * 32 + quad * 8];
        #pragma unroll
        for (int mi = 0; mi < 4; ++mi)
            #pragma unroll
            for (int ni = 0; ni < 4; ++ni)
                acc[mi][ni] = __builtin_amdgcn_mfma_f32_16x16x32_bf16(
                    af[mi], bfr[ni], acc[mi][ni], 0, 0, 0);
    }

    #pragma unroll
    for (int mi = 0; mi < 4; ++mi) {
        #pragma unroll
        for (int ni = 0; ni < 4; ++ni) {
            int col = col0 + wc + ni * 16 + l16;
            float bb = bias[col];
            #pragma unroll
            for (int r = 0; r < 4; ++r) {
                int row = row0 + wr + mi * 16 + quad * 4 + r;
                float v = acc[mi][ni][r] + bb;
                if (RELU) v = v > 0.f ? v : 0.f;
                if (OUT_MODE == 0) {
                    ((float*)Cout)[(size_t)row * N + col] = v;
                } else if (OUT_MODE == 1) {
                    int tensor = col >> 8;          // 0=q 1=k 2=v
                    int c2 = col & 255;
                    int b  = row >> 11, l = row & (LL - 1);
                    int hh = c2 >> 5,  dh = c2 & 31;
                    int bh = b * NH + hh;
                    size_t bi = (((size_t)bh * LL + l) << 5) + dh;
                    ((float*)Cout)[(size_t)tensor * (BB*NH*LL*DH) + bi] = v;
                    if (tensor == 1)   // kT[l][bh][d] bf16 for metric
                        ((ushort_t*)aux)[(((size_t)l << 6) + bh) * 32 + dh] = f2b(v);
                } else if (OUT_MODE == 2) {
                    ((ushort_t*)Cout)[(size_t)row * N + col] = f2b(v);
                } else {
                    ((float*)Cout)[(size_t)row * N + col] = v;
                    ((ushort_t*)aux)[(size_t)row * N + col] = f2b(v);
                }
            }
        }
    }
}

// ---------------------------------------------------------------------------
// Fused GEMM (Mx256, K param) + residual + LayerNorm:
//   h = LN(h + A@Bt^T + bias) * g + beta ; writes h fp32 + hb bf16.
// 32x256 tile, grid M/32 = 512 blocks (2/CU), 4 waves (wave = 64 cols).
// ---------------------------------------------------------------------------
__global__ __launch_bounds__(256)
void gemmln_k(const ushort_t* __restrict__ A, const ushort_t* __restrict__ Bt,
              const float* __restrict__ bias, float* __restrict__ h,
              ushort_t* __restrict__ hb, const float* __restrict__ g,
              const float* __restrict__ beta, int K)
{
    __shared__ ushort_t Asl[32 * 32];    // 2 KB
    __shared__ ushort_t Bsl[256 * 32];   // 16 KB
    __shared__ float rs[4][32], rs2[4][32];

    const int t    = threadIdx.x;
    const int lane = t & 63;
    const int wv   = t >> 6;
    const int row0 = blockIdx.x * 32;
    const int wc   = wv * 64;
    const int quad = lane >> 4;
    const int l16  = lane & 15;

    f32x4 acc[2][4];
    #pragma unroll
    for (int i = 0; i < 2; ++i)
        #pragma unroll
        for (int j = 0; j < 4; ++j)
            acc[i][j] = 0.f;

    for (int k0 = 0; k0 < K; k0 += 32) {
        __syncthreads();
        if (wv < 2) {   // A tile: 32 rows x 32 k = 2 KB, waves 0-1
            const ushort_t* ga = A + (size_t)(row0 + (t >> 2)) * K + k0 + (t & 3) * 8;
            gload16(ga, (const char*)Asl + wv * 1024);
        }
        #pragma unroll
        for (int r = 0; r < 4; ++r) {   // B tile: 256 rows x 32 k = 16 KB
            int gg = r * 256 + t;
            const ushort_t* gb = Bt + (size_t)(gg >> 2) * K + k0 + (gg & 3) * 8;
            gload16(gb, (const char*)Bsl + (r * 256 + wv * 64) * 16);
        }
        __syncthreads();

        short8 af[2], bfr[4];
        #pragma unroll
        for (int mi = 0; mi < 2; ++mi)
            af[mi] = *(const short8*)&Asl[(mi * 16 + l16) * 32 + quad * 8];
        #pragma unroll
        for (int ni = 0; ni < 4; ++ni)
            bfr[ni] = *(const short8*)&Bsl[(wc + ni * 16 + l16) * 32 + quad * 8];
        #pragma unroll
        for (int mi = 0; mi < 2; ++mi)
            #pragma unroll
            for (int ni = 0; ni < 4; ++ni)
                acc[mi][ni] = __builtin_amdgcn_mfma_f32_16x16x32_bf16(
                    af[mi], bfr[ni], acc[mi][ni], 0, 0, 0);
    }

    // x = acc + bias + h_old; accumulate row stats
    float gcol[4], bcol[4];
    #pragma unroll
    for (int ni = 0; ni < 4; ++ni) {
        int col = wc + ni * 16 + l16;
        gcol[ni] = g[col];
        bcol[ni] = beta[col];
    }
    float ps[2][4], ps2[2][4];
    #pragma unroll
    for (int mi = 0; mi < 2; ++mi) {
        #pragma unroll
        for (int r = 0; r < 4; ++r) {
            int row = row0 + mi * 16 + quad * 4 + r;
            float s = 0.f, s2 = 0.f;
            #pragma unroll
            for (int ni = 0; ni < 4; ++ni) {
                int col = wc + ni * 16 + l16;
                float v = acc[mi][ni][r] + bias[col] + h[(size_t)row * DM + col];
                acc[mi][ni][r] = v;
                s += v;
                s2 += v * v;
            }
            ps[mi][r] = s;
            ps2[mi][r] = s2;
        }
    }
    // reduce over the 16 lanes (l16) sharing this quad
    #pragma unroll
    for (int off = 1; off < 16; off <<= 1) {
        #pragma unroll
        for (int mi = 0; mi < 2; ++mi)
            #pragma unroll
            for (int r = 0; r < 4; ++r) {
                ps[mi][r]  += __shfl_xor(ps[mi][r],  off, 16);
                ps2[mi][r] += __shfl_xor(ps2[mi][r], off, 16);
            }
    }
    if (l16 == 0) {
        #pragma unroll
        for (int mi = 0; mi < 2; ++mi)
            #pragma unroll
            for (int r = 0; r < 4; ++r) {
                int lrow = mi * 16 + quad * 4 + r;
                rs[wv][lrow]  = ps[mi][r];
                rs2[wv][lrow] = ps2[mi][r];
            }
    }
    __syncthreads();

    #pragma unroll
    for (int mi = 0; mi < 2; ++mi) {
        #pragma unroll
        for (int r = 0; r < 4; ++r) {
            int lrow = mi * 16 + quad * 4 + r;
            int row  = row0 + lrow;
            float tot  = rs[0][lrow] + rs[1][lrow] + rs[2][lrow] + rs[3][lrow];
            float tot2 = rs2[0][lrow] + rs2[1][lrow] + rs2[2][lrow] + rs2[3][lrow];
            float mean = tot * (1.f / (float)DM);
            float var  = tot2 * (1.f / (float)DM) - mean * mean;
            float inv  = 1.0f / sqrtf(var + 1e-5f);
            #pragma unroll
            for (int ni = 0; ni < 4; ++ni) {
                int col = wc + ni * 16 + l16;
                float val = (acc[mi][ni][r] - mean) * inv * gcol[ni] + bcol[ni];
                h[(size_t)row * DM + col]  = val;
                hb[(size_t)row * DM + col] = f2b(val);
            }
        }
    }
}

// ---------------------------------------------------------------------------
// fused preproc: all weight transposes+cvt, bias pack, x cvt in ONE dispatch.
// ---------------------------------------------------------------------------
__device__ inline void tcvt_dev(float (*tile)[33], const float* __restrict__ src,
                                ushort_t* __restrict__ dst, int K, int N,
                                int matStride, int bi)
{
    int tilesN = N >> 5;
    int tpm = (K >> 5) * tilesN;
    int m   = bi / tpm;
    int tid = bi % tpm;
    int k0 = (tid / tilesN) << 5, n0 = (tid % tilesN) << 5;
    const float* s = src + (size_t)m * K * N;
    ushort_t*    d = dst + (size_t)m * matStride;
    int r = threadIdx.x >> 5, c = threadIdx.x & 31;
    #pragma unroll
    for (int i = 0; i < 4; ++i)
        tile[r + 8 * i][c] = s[(size_t)(k0 + r + 8 * i) * N + n0 + c];
    __syncthreads();
    #pragma unroll
    for (int i = 0; i < 4; ++i)
        d[(size_t)(n0 + r + 8 * i) * K + k0 + c] = f2b(tile[c][r + 8 * i]);
}

__global__ __launch_bounds__(256)
void preproc_k(const float* __restrict__ wq, const float* __restrict__ wk,
               const float* __restrict__ wv, const float* __restrict__ wo,
               const float* __restrict__ wf1, const float* __restrict__ wf2,
               const float* __restrict__ w_in,
               const float* __restrict__ bq, const float* __restrict__ bk,
               const float* __restrict__ bv, const float* __restrict__ x,
               ushort_t* __restrict__ wqkvT, ushort_t* __restrict__ woT,
               ushort_t* __restrict__ wf1T, ushort_t* __restrict__ wf2T,
               ushort_t* __restrict__ w_inT, float* __restrict__ bqkv,
               ushort_t* __restrict__ xb16)
{
    __shared__ float tile[32][33];
    int b = blockIdx.x;
    if (b < 512) {
        int which = b >> 7, lb = b & 127;
        const float* src = which == 0 ? wq : which == 1 ? wk : which == 2 ? wv : wo;
        ushort_t* dst = which == 0 ? wqkvT : which == 1 ? wqkvT + 65536
                       : which == 2 ? wqkvT + 131072 : woT;
        int stride = which == 3 ? 65536 : 768 * 256;
        tcvt_dev(tile, src, dst, DM, DM, stride, lb);
    } else if (b < 1024) {
        tcvt_dev(tile, wf1, wf1T, DM, DFF, 1024 * 256, b - 512);
    } else if (b < 1536) {
        tcvt_dev(tile, wf2, wf2T, DFF, DM, 256 * 1024, b - 1024);
    } else if (b < 1544) {
        tcvt_dev(tile, w_in, w_inT, 32, DM, 256 * 32, b - 1536);
    } else if (b < 1550) {
        int t = (b - 1544) * 256 + threadIdx.x;
        int i = t / 768, j = t % 768;
        const float* s = j < 256 ? bq : (j < 512 ? bk : bv);
        bqkv[t] = s[i * 256 + (j & 255)];
    } else {
        int tid = (b - 1550) * 256 + threadIdx.x;
        float4 v = ((const float4*)x)[tid];
        unsigned int lo = f2b(v.x) | ((unsigned int)f2b(v.y) << 16);
        unsigned int hi = f2b(v.z) | ((unsigned int)f2b(v.w) << 16);
        ((uint2*)xb16)[tid] = make_uint2(lo, hi);
    }
}

// ---------------------------------------------------------------------------
// metric v3: lane = bh, wave = one query position l. kT[l][bh][d] reads are
// fully coalesced (lane-stride 64 B). q row in registers. grid 512 x 256.
// ---------------------------------------------------------------------------
__global__ __launch_bounds__(256)
void metric2_k(const float* __restrict__ qb, const ushort_t* __restrict__ kT,
               const int* __restrict__ idx, float* __restrict__ Mout)
{
    __shared__ float mst[64][5];
    int t = threadIdx.x;
    int w = t >> 6, lane = t & 63;
    int l = blockIdx.x * 4 + w;

    const float4* qr = (const float4*)(qb + ((size_t)(lane * LL + l) << 5));
    float4 q[8];
    #pragma unroll
    for (int i = 0; i < 8; ++i) q[i] = qr[i];

    int r40 = idx[l * SS + (lane < SS ? lane : SS - 1)];

    float mx = -3e38f, sm = 0.f;
    for (int s = 0; s < SS; ++s) {
        int r = __shfl(r40, s, 64);
        const uint4* kr = (const uint4*)(kT + (((size_t)r << 6) + lane) * 32);
        float d = 0.f;
        #pragma unroll
        for (int ww = 0; ww < 4; ++ww) {
            uint4 kv = kr[ww];
            float4 qa = q[2 * ww], qb2 = q[2 * ww + 1];
            d = fmaf(__uint_as_float(kv.x << 16),         qa.x, d);
            d = fmaf(__uint_as_float(kv.x & 0xffff0000u), qa.y, d);
            d = fmaf(__uint_as_float(kv.y << 16),         qa.z, d);
            d = fmaf(__uint_as_float(kv.y & 0xffff0000u), qa.w, d);
            d = fmaf(__uint_as_float(kv.z << 16),         qb2.x, d);
            d = fmaf(__uint_as_float(kv.z & 0xffff0000u), qb2.y, d);
            d = fmaf(__uint_as_float(kv.w << 16),         qb2.z, d);
            d = fmaf(__uint_as_float(kv.w & 0xffff0000u), qb2.w, d);
        }
        mx = fmaxf(mx, d);
        sm += d;
    }
    mst[lane][w] = mx - sm * (1.0f / (float)LL);
    __syncthreads();

    int bh = t >> 2, ls = t & 3;
    Mout[(size_t)bh * LL + blockIdx.x * 4 + ls] = mst[bh][ls];
}

// ---------------------------------------------------------------------------
// topk stage 1: wave-synchronous per-slice top-40 (no barriers). grid 128.
// ---------------------------------------------------------------------------
__global__ __launch_bounds__(256)
void topk1_k(const float* __restrict__ Mout,
             float* __restrict__ cand_v, int* __restrict__ cand_i)
{
    int lane = threadIdx.x & 63;
    int slg  = blockIdx.x * 4 + (threadIdx.x >> 6);   // 0..511
    int bh   = slg >> 3;
    int l0   = (slg & 7) << 8;

    float v[4];
    #pragma unroll
    for (int i = 0; i < 4; ++i)
        v[i] = Mout[(size_t)bh * LL + l0 + i * 64 + lane];

    for (int r = 0; r < UU; ++r) {
        float bv = -3e38f; int bi = 1 << 30;
        #pragma unroll
        for (int i = 0; i < 4; ++i) {
            int idx = l0 + i * 64 + lane;
            if (v[i] > bv || (v[i] == bv && idx < bi)) { bv = v[i]; bi = idx; }
        }
        #pragma unroll
        for (int off = 32; off > 0; off >>= 1) {
            float ov = __shfl_down(bv, off, 64);
            int   oi = __shfl_down(bi, off, 64);
            if (ov > bv || (ov == bv && oi < bi)) { bv = ov; bi = oi; }
        }
        bv = __shfl(bv, 0, 64);
        bi = __shfl(bi, 0, 64);
        if (lane == 0) {
            cand_v[slg * UU + r] = bv;
            cand_i[slg * UU + r] = bi;
        }
        int rel = bi - l0;
        if ((rel & 63) == lane) v[rel >> 6] = -3e38f;
    }
}

// topk stage 2: rank-select top-40 from 320 candidates per bh.
__global__ __launch_bounds__(256)
void topk2_k(const float* __restrict__ cand_v, const int* __restrict__ cand_i,
             int* __restrict__ top)
{
    __shared__ float cv[320];
    __shared__ int   ci[320];
    int bh = blockIdx.x, t = threadIdx.x;
    for (int i = t; i < 320; i += 256) {
        cv[i] = cand_v[bh * 320 + i];
        ci[i] = cand_i[bh * 320 + i];
    }
    __syncthreads();
    for (int c = t; c < 320; c += 256) {
        float mv = cv[c]; int mi = ci[c];
        int rank = 0;
        for (int j = 0; j < 320; ++j)
            rank += (cv[j] > mv) || (cv[j] == mv && ci[j] < mi);
        if (rank < UU) top[bh * UU + rank] = mi;
    }
}

// vmean partials: grid 512 (bh x 8 slices)
__global__ __launch_bounds__(256)
void vmeanp_k(const float* __restrict__ vb, float* __restrict__ vmeP)
{
    __shared__ float red[8][32];
    int blk = blockIdx.x;
    int bh = blk >> 3, sl = blk & 7;
    int t = threadIdx.x;
    int d = t & 31, part = t >> 5;
    const float* base = vb + ((size_t)(bh * LL + sl * 256 + part * 32) << 5);
    float s = 0.f;
    #pragma unroll 8
    for (int i = 0; i < 32; ++i) s += base[(i << 5) + d];
    red[part][d] = s;
    __syncthreads();
    if (t < 32) {
        float tot = 0.f;
        #pragma unroll
        for (int p = 0; p < 8; ++p) tot += red[p][t];
        vmeP[blk * 32 + t] = tot;
    }
}

__global__ __launch_bounds__(256)
void vfin_k(const float* __restrict__ vmeP, float* __restrict__ vme)
{
    int tid = blockIdx.x * 256 + threadIdx.x;   // < 2048
    int bh = tid >> 5, d = tid & 31;
    float s = 0.f;
    #pragma unroll
    for (int sl = 0; sl < 8; ++sl) s += vmeP[(bh * 8 + sl) * 32 + d];
    vme[tid] = s * (1.f / (float)LL);
}

// ---------------------------------------------------------------------------
// attnupd: block = bh*NSL + slice (512 blocks), 256 l per slice.
// ---------------------------------------------------------------------------
__global__ __launch_bounds__(256)
void attnupd_k(const float* __restrict__ qb, const float* __restrict__ kb,
               const float* __restrict__ vb, const int* __restrict__ top,
               float* __restrict__ mP, float* __restrict__ sP,
               float* __restrict__ OP)
{
    __shared__ float qs[UU * 32];        // 5 KB
    __shared__ float sc[UU * 256];       // 40 KB
    __shared__ float msh[UU];

    int blk = blockIdx.x;
    int sl  = blk & (NSL - 1);
    int bh  = blk >> 3;
    int t   = threadIdx.x;
    int l0  = sl << 8;

    for (int i = t; i < UU * 32; i += 256) {
        int j = i >> 5, dd = i & 31;
        qs[i] = qb[((size_t)(bh * LL + top[bh * UU + j]) << 5) + dd];
    }

    const float4* kr = (const float4*)(kb + ((size_t)(bh * LL + l0 + t) << 5));
    float4 k4[8];
    #pragma unroll
    for (int i = 0; i < 8; ++i) k4[i] = kr[i];
    __syncthreads();

    const float scale = 0.17677669529663687f;   // 1/sqrt(32)
    #pragma unroll 4
    for (int j = 0; j < UU; ++j) {
        float ds = 0.f;
        #pragma unroll
        for (int i = 0; i < 8; ++i) {
            float4 qv = *(const float4*)&qs[j * 32 + 4 * i];   // broadcast
            ds = fmaf(qv.x, k4[i].x, ds);
            ds = fmaf(qv.y, k4[i].y, ds);
            ds = fmaf(qv.z, k4[i].z, ds);
            ds = fmaf(qv.w, k4[i].w, ds);
        }
        sc[j * 256 + t] = ds * scale;
    }
    __syncthreads();

    int j8 = t >> 5, d = t & 31;
    #pragma unroll
    for (int g = 0; g < 5; ++g) {
        int j = g * 8 + j8;
        float4 a = *(const float4*)&sc[j * 256 + 4 * d];
        float4 b = *(const float4*)&sc[j * 256 + 128 + 4 * d];
        float m = fmaxf(fmaxf(fmaxf(a.x, a.y), fmaxf(a.z, a.w)),
                        fmaxf(fmaxf(b.x, b.y), fmaxf(b.z, b.w)));
        #pragma unroll
        for (int off = 16; off > 0; off >>= 1)
            m = fmaxf(m, __shfl_down(m, off, 64));
        if (d == 0) msh[j] = m;
    }
    __syncthreads();

    #pragma unroll 8
    for (int i = t; i < UU * 256; i += 256) {
        int j = i >> 8;
        sc[i] = __expf(sc[i] - msh[j]);
    }
    __syncthreads();

    int pq = bh * NSL + sl;

    #pragma unroll
    for (int g = 0; g < 5; ++g) {
        int j = g * 8 + j8;
        float4 a = *(const float4*)&sc[j * 256 + 4 * d];
        float4 b = *(const float4*)&sc[j * 256 + 128 + 4 * d];
        float s = a.x + a.y + a.z + a.w + b.x + b.y + b.z + b.w;
        #pragma unroll
        for (int off = 16; off > 0; off >>= 1)
            s += __shfl_down(s, off, 64);
        if (d == 0) { sP[pq * UU + j] = s; mP[pq * UU + j] = msh[j]; }
    }

    const float* vbase = vb + ((size_t)(bh * LL + l0) << 5) + d;
    float acc[5] = {0.f, 0.f, 0.f, 0.f, 0.f};
    #pragma unroll 4
    for (int i = 0; i < 64; ++i) {
        float v0 = vbase[(4 * i + 0) << 5];
        float v1 = vbase[(4 * i + 1) << 5];
        float v2 = vbase[(4 * i + 2) << 5];
        float v3 = vbase[(4 * i + 3) << 5];
        #pragma unroll
        for (int g = 0; g < 5; ++g) {
            float4 e4 = *(const float4*)&sc[(g * 8 + j8) * 256 + 4 * i];
            acc[g] = fmaf(e4.x, v0, acc[g]);
            acc[g] = fmaf(e4.y, v1, acc[g]);
            acc[g] = fmaf(e4.z, v2, acc[g]);
            acc[g] = fmaf(e4.w, v3, acc[g]);
        }
    }
    #pragma unroll
    for (int g = 0; g < 5; ++g)
        OP[((size_t)pq * UU + g * 8 + j8) * 32 + d] = acc[g];
}

// merge NSL slice-partials, normalize, scatter bf16 into ctx
__global__ __launch_bounds__(256)
void combine_k(const float* __restrict__ mP, const float* __restrict__ sP,
               const float* __restrict__ OP, const int* __restrict__ top,
               ushort_t* __restrict__ ctxb)
{
    int tid = blockIdx.x * 256 + threadIdx.x;   // < 64*40*32
    int d  = tid & 31;
    int j  = (tid >> 5) % UU;
    int bh = tid / (UU * 32);
    float M = -3e38f;
    #pragma unroll
    for (int q = 0; q < NSL; ++q) M = fmaxf(M, mP[(bh * NSL + q) * UU + j]);
    float S = 0.f, O = 0.f;
    #pragma unroll
    for (int q = 0; q < NSL; ++q) {
        float w = __expf(mP[(bh * NSL + q) * UU + j] - M);
        S = fmaf(sP[(bh * NSL + q) * UU + j], w, S);
        O = fmaf(OP[((size_t)(bh * NSL + q) * UU + j) * 32 + d], w, O);
    }
    float u = O / S;
    int qi = top[bh * UU + j];
    int b = bh >> 3, hh = bh & 7;
    ctxb[(((size_t)(b * LL + qi)) << 8) + (hh << 5) + d] = f2b(u);
}

// ctx bf16 fill with vmean broadcast (2 elems/thread packed)
__global__ __launch_bounds__(256)
void fill2_k(ushort_t* __restrict__ ctxb, const float* __restrict__ vmean)
{
    int tid = blockIdx.x * 256 + threadIdx.x;
    int pr = tid & 127;
    int b  = tid >> 18;
    float v0 = vmean[(b << 8) + pr * 2];
    float v1 = vmean[(b << 8) + pr * 2 + 1];
    ((unsigned int*)ctxb)[tid] = (unsigned int)f2b(v0) | ((unsigned int)f2b(v1) << 16);
}

__global__ __launch_bounds__(512)
void head_k(const float* __restrict__ h, const float* __restrict__ w1,
            const float* __restrict__ b1, const float* __restrict__ w2,
            const float* __restrict__ b2, float* __restrict__ out)
{
    int t = threadIdx.x;
    int b = t >> 6, j = t & 63;
    const float* hr = h + ((size_t)(b * LL + (LL - 1))) * DM;
    float s = 0.f;
    for (int kk = 0; kk < DM; ++kk) s = fmaf(hr[kk], w1[kk * 64 + j], s);
    s += b1[j];
    s = s > 0.f ? s : 0.f;
    float contrib = s * w2[j];
    #pragma unroll
    for (int off = 32; off > 0; off >>= 1) contrib += __shfl_down(contrib, off);
    if (j == 0) out[b] = contrib + b2[0];
}

extern "C" void kernel_launch(void* const* d_in, const int* in_sizes, int n_in,
                              void* d_out, int out_size, void* d_ws, size_t ws_size,
                              hipStream_t stream)
{
    const float* x    = (const float*)d_in[0];
    const int*   idx  = (const int*)  d_in[1];
    const float* w_in = (const float*)d_in[2];
    const float* b_in = (const float*)d_in[3];
    const float* wq   = (const float*)d_in[4];
    const float* bq   = (const float*)d_in[5];
    const float* wk   = (const float*)d_in[6];
    const float* bk   = (const float*)d_in[7];
    const float* wv   = (const float*)d_in[8];
    const float* bv   = (const float*)d_in[9];
    const float* wo   = (const float*)d_in[10];
    const float* bo   = (const float*)d_in[11];
    const float* wf1  = (const float*)d_in[12];
    const float* bf1  = (const float*)d_in[13];
    const float* wf2  = (const float*)d_in[14];
    const float* bf2  = (const float*)d_in[15];
    const float* g1   = (const float*)d_in[16];
    const float* be1  = (const float*)d_in[17];
    const float* g2   = (const float*)d_in[18];
    const float* be2  = (const float*)d_in[19];
    const float* wfc1 = (const float*)d_in[20];
    const float* bfc1 = (const float*)d_in[21];
    const float* wfc2 = (const float*)d_in[22];
    const float* bfc2 = (const float*)d_in[23];
    float* out = (float*)d_out;

    float* ws = (float*)d_ws;
    float*    h     = ws;                          // [0, 4194304)
    float*    qkv   = ws + 4194304;                // [4194304, 16777216)
    float*    qb    = qkv;
    float*    kb    = qkv + 4194304;
    float*    vb    = qkv + 8388608;
    // attn scratch region (4194304 floats), all dead outside attention phase
    float*    attnS = ws + 16777216;
    ushort_t* kT16  = (ushort_t*)attnS;            //   fl [0, 2097152): kT[l][bh][d] bf16
    float*    Mbuf  = attnS + 2097152;             //   fl [2097152, 2228224)
    float*    candv = attnS + 2228224;             //   20480
    int*      candi = (int*)(attnS + 2248704);     //   20480
    float*    vmeP  = attnS + 2269184;             //   16384
    float*    OP    = attnS + 2285568;             //   655360
    float*    mP    = attnS + 2940928;             //   20480
    float*    sP    = attnS + 2961408;             //   20480 (ends 2981888 < 4194304)
    // long-lived scratch — offsets in FLOATS
    float*    scr   = ws + 20971520;
    ushort_t* xb16  = (ushort_t*)scr;              //   fl [0, 262144)
    float*    vme   = scr + 262144;                //   fl [262144, 264192)
    int*      top   = (int*)(scr + 264192);        //   fl [264192, 266752)
    ushort_t* hb    = (ushort_t*)(scr + 266752);   //   fl [266752, 2363904)
    ushort_t* wqkvT = (ushort_t*)(scr + 2363904);  //   fl [2363904, 2560512)
    ushort_t* woT   = (ushort_t*)(scr + 2560512);  //   fl [2560512, 2626048)
    ushort_t* wf1T  = (ushort_t*)(scr + 2626048);  //   fl [2626048, 2888192)
    ushort_t* wf2T  = (ushort_t*)(scr + 2888192);  //   fl [2888192, 3150336)
    ushort_t* w_inT = (ushort_t*)(scr + 3150336);  //   fl [3150336, 3154432)
    float*    bqkv  = scr + 3154432;               //   fl [3154432, 3155968)
    ushort_t* ctxb  = (ushort_t*)qkv;              // aliases dead q
    ushort_t* ffbb  = (ushort_t*)(qkv + 2097152);  // aliases dead q/k/v

    dim3 blk(256);

    preproc_k<<<dim3(2062), blk, 0, stream>>>(
        wq, wk, wv, wo, wf1, wf2, w_in, bq, bk, bv, x,
        wqkvT, woT, wf1T, wf2T, w_inT, bqkv, xb16);

    gemm_mfma<0,3><<<dim3(BL/128, 2), blk, 0, stream>>>(
        xb16, w_inT, b_in, (void*)h, (void*)hb, BL, DM, 32);

    for (int i = 0; i < 2; ++i) {
        gemm_mfma<0,1><<<dim3(BL/128, 6), blk, 0, stream>>>(
            hb, wqkvT + (size_t)i*768*256, bqkv + i*768, (void*)qkv, (void*)kT16,
            BL, 768, DM);

        metric2_k<<<dim3(512), blk, 0, stream>>>(qb, kT16, idx + (size_t)i*LL*SS, Mbuf);
        topk1_k<<<dim3(128), blk, 0, stream>>>(Mbuf, candv, candi);
        topk2_k<<<dim3(BB*NH), blk, 0, stream>>>(candv, candi, top);
        vmeanp_k<<<dim3(512), blk, 0, stream>>>(vb, vmeP);
        vfin_k<<<dim3(8), blk, 0, stream>>>(vmeP, vme);
        attnupd_k<<<dim3(BB*NH*NSL), blk, 0, stream>>>(qb, kb, vb, top, mP, sP, OP);

        fill2_k<<<dim3(BL*DM/512), blk, 0, stream>>>(ctxb, vme);
        combine_k<<<dim3(BB*NH*UU*DH/256), blk, 0, stream>>>(mP, sP, OP, top, ctxb);

        // fused O-proj + residual + LN1
        gemmln_k<<<dim3(BL/32), blk, 0, stream>>>(
            ctxb, woT + (size_t)i*256*256, bo + i*DM, h, hb,
            g1 + i*DM, be1 + i*DM, DM);

        gemm_mfma<1,2><<<dim3(BL/128, 8), blk, 0, stream>>>(
            hb, wf1T + (size_t)i*1024*256, bf1 + i*DFF, (void*)ffbb, nullptr, BL, DFF, DM);

        // fused FF2 + residual + LN2
        gemmln_k<<<dim3(BL/32), blk, 0, stream>>>(
            ffbb, wf2T + (size_t)i*256*1024, bf2 + i*DM, h, hb,
            g2 + i*DM, be2 + i*DM, DFF);
    }

    head_k<<<dim3(1), dim3(512), 0, stream>>>(h, wfc1, bfc1, wfc2, bfc2, out);
}